// Round 6
// baseline (296.607 us; speedup 1.0000x reference)
//
#include <hip/hip_runtime.h>
#include <hip/hip_bf16.h>

// GraphEncoder: 2-layer GNN, edge-MLP + scatter-mean.
//   cat(x_dst,x_src)@Wa = (x@Wa_top)[dst] + (x@Wa_bot)[src]
//   mean_agg(relu(pre)@Wb + bb) = mean_agg(relu(pre))@Wb + (cnt>0)*bb
// R6: agg restructured as 64-feature column-slice passes so the gather array
//     (2.56 MB/slice) fits each XCD's 4MB L2 (R5 FETCH showed ~60% L2 miss on the
//     10MB Pbot). Wave-per-node, 2 edges per load slot (32 lanes x ushort2),
//     16 edges in flight. Weight prep merged into one kernel (-5 dispatches).

#define NODE_DIM 128
#define HID 256
#define OUTD 128

typedef __attribute__((ext_vector_type(8))) short bf16x8;
typedef __attribute__((ext_vector_type(4))) float f32x4;

__device__ __forceinline__ float bf2f(ushort u) {
    return __uint_as_float(((unsigned)u) << 16);
}
__device__ __forceinline__ ushort f2bf_rne(float x) {
    unsigned u = __float_as_uint(x);
    unsigned r = u + 0x7fffu + ((u >> 16) & 1u);
    return (ushort)(r >> 16);
}
__device__ __forceinline__ void split2(float x, ushort& hi, ushort& lo) {
    hi = f2bf_rne(x);
    float hf = __uint_as_float(((unsigned)hi) << 16);
    lo = f2bf_rne(x - hf);
}

// ---------------- utility kernels ----------------

__global__ void zero_int_kernel(int* __restrict__ p, int n) {
    int i = blockIdx.x * blockDim.x + threadIdx.x;
    if (i < n) p[i] = 0;
}

__global__ void hist_kernel(const int* __restrict__ dst, int* __restrict__ cnt, int E) {
    int e = blockIdx.x * blockDim.x + threadIdx.x;
    if (e < E) atomicAdd(&cnt[dst[e]], 1);
}

// exclusive scan over cnt -> row_ptr + cursor; single block, shuffle-based
__global__ __launch_bounds__(1024) void scan_kernel(const int* __restrict__ cnt,
                                                    int* __restrict__ row_ptr,
                                                    int* __restrict__ cursor, int N) {
    __shared__ int wsum[16];
    const int tid = threadIdx.x;
    const int lane = tid & 63;
    const int wv = tid >> 6;
    int running = 0;
    for (int base = 0; base < N; base += 1024) {
        const int i = base + tid;
        const int v = (i < N) ? cnt[i] : 0;
        int x = v;
#pragma unroll
        for (int off = 1; off < 64; off <<= 1) {
            int t = __shfl_up(x, off, 64);
            if (lane >= off) x += t;
        }
        if (lane == 63) wsum[wv] = x;
        __syncthreads();
        if (wv == 0) {
            int s = (lane < 16) ? wsum[lane] : 0;
#pragma unroll
            for (int off = 1; off < 16; off <<= 1) {
                int t = __shfl_up(s, off, 64);
                if (lane >= off) s += t;
            }
            if (lane < 16) wsum[lane] = s;
        }
        __syncthreads();
        const int woff = (wv > 0) ? wsum[wv - 1] : 0;
        const int total = wsum[15];
        if (i < N) {
            int ex = running + woff + x - v;
            row_ptr[i] = ex;
            cursor[i] = ex;
        }
        running += total;
        __syncthreads();
    }
    if (tid == 0) row_ptr[N] = running;
}

__global__ void scatter_kernel(const int* __restrict__ src, const int* __restrict__ dst,
                               int* __restrict__ cursor, int* __restrict__ csr, int E) {
    int e = blockIdx.x * blockDim.x + threadIdx.x;
    if (e < E) {
        int p = atomicAdd(&cursor[dst[e]], 1);
        csr[p] = src[e];
    }
}

// split f32 array -> hi/lo bf16 (4 elems/thread)
__global__ void split_kernel(const float* __restrict__ x, ushort* __restrict__ hi,
                             ushort* __restrict__ lo, int n4) {
    int i = blockIdx.x * blockDim.x + threadIdx.x;
    if (i >= n4) return;
    float4 v = ((const float4*)x)[i];
    ushort4 h, l;
    split2(v.x, h.x, l.x);
    split2(v.y, h.y, l.y);
    split2(v.z, h.z, l.z);
    split2(v.w, h.w, l.w);
    ((ushort4*)hi)[i] = h;
    ((ushort4*)lo)[i] = l;
}

// All four weight transposes+splits in one kernel.
// T1a [512][128] (merged Wa top|bottom, transposed), T1b [256][256],
// T2a [256][256] (merged), T2b [128][128].
__global__ void prep_weights(const float* __restrict__ W1a, const float* __restrict__ W1b,
                             const float* __restrict__ W2a, const float* __restrict__ W2b,
                             ushort* __restrict__ T1a_h, ushort* __restrict__ T1a_l,
                             ushort* __restrict__ T1b_h, ushort* __restrict__ T1b_l,
                             ushort* __restrict__ T2a_h, ushort* __restrict__ T2a_l,
                             ushort* __restrict__ T2b_h, ushort* __restrict__ T2b_l) {
    int i = blockIdx.x * blockDim.x + threadIdx.x;
    float v;
    ushort *ph, *pl;
    int o;
    if (i < 65536) {  // T1a [n<512][k<128]; src W1a [256][256]
        int n = i >> 7, k = i & 127;
        v = (n < 256) ? W1a[k * 256 + n] : W1a[(128 + k) * 256 + (n - 256)];
        ph = T1a_h; pl = T1a_l; o = i;
    } else if (i < 131072) {  // T1b [n<256][k<256]; src W1b [256][256]
        int j = i - 65536;
        int n = j >> 8, k = j & 255;
        v = W1b[k * 256 + n];
        ph = T1b_h; pl = T1b_l; o = j;
    } else if (i < 196608) {  // T2a [n<256][k<256]; src W2a [512][128]
        int j = i - 131072;
        int n = j >> 8, k = j & 255;
        v = (n < 128) ? W2a[k * 128 + n] : W2a[(256 + k) * 128 + (n - 128)];
        ph = T2a_h; pl = T2a_l; o = j;
    } else if (i < 212992) {  // T2b [n<128][k<128]; src W2b [128][128]
        int j = i - 196608;
        int n = j >> 7, k = j & 127;
        v = W2b[k * 128 + n];
        ph = T2b_h; pl = T2b_l; o = j;
    } else {
        return;
    }
    ushort h, l;
    split2(v, h, l);
    ph[o] = h;
    pl[o] = l;
}

// ---------------- bf16 3-pass MFMA GEMM ----------------
// A[M][K] hi/lo bf16; B transposed [Nc][K] hi/lo. Tile BM=128,BN=64,BK=32; 4 waves.
// MODE 0: f32 out (+bias,+gate,+relu). MODE 1: dual — col<nsplit -> f32+bias;
// col>=nsplit -> bf16. MODE 2: hi/lo bf16 out (+bias,+gate,+relu).

#define GBM 128
#define GBN 64
#define GBK 32
#define LDSW 40

template <int MODE>
__global__ __launch_bounds__(256) void gemm_bf3(
    const ushort* __restrict__ Ahi, const ushort* __restrict__ Alo, int M, int K,
    const ushort* __restrict__ BThi, const ushort* __restrict__ BTlo,
    const float* __restrict__ bias, const int* __restrict__ gate, int relu,
    float* __restrict__ Cf, ushort* __restrict__ Chi, ushort* __restrict__ Clo,
    int Nc, int nsplit) {
    __shared__ ushort sAh[GBM * LDSW], sAl[GBM * LDSW];
    __shared__ ushort sBh[GBN * LDSW], sBl[GBN * LDSW];

    const int tid = threadIdx.x;
    const int lane = tid & 63;
    const int w = tid >> 6;
    const int wm = w >> 1, wn = w & 1;
    const int r16 = lane & 15, kg = lane >> 4;
    const int m0 = blockIdx.x * GBM;
    const int n0 = blockIdx.y * GBN;

    const int arow = tid >> 1, ahalf = tid & 1;   // A: 2 thr/row, 16 ushorts (2x int4)
    const int brow = tid >> 2, bchunk = tid & 3;  // B: 4 thr/row, 8 ushorts (1x int4)

    f32x4 acc[4][2];
#pragma unroll
    for (int i = 0; i < 4; i++)
#pragma unroll
        for (int j = 0; j < 2; j++) acc[i][j] = (f32x4)0.f;

    for (int kt = 0; kt < K; kt += GBK) {
        {
            const int gr = m0 + arow;
            int4 h0 = make_int4(0, 0, 0, 0), h1 = h0, l0 = h0, l1 = h0;
            if (gr < M) {
                const size_t go = (size_t)gr * K + kt + ahalf * 16;
                h0 = *(const int4*)(Ahi + go);
                h1 = *(const int4*)(Ahi + go + 8);
                l0 = *(const int4*)(Alo + go);
                l1 = *(const int4*)(Alo + go + 8);
            }
            ushort* dh = sAh + arow * LDSW + ahalf * 16;
            ushort* dl = sAl + arow * LDSW + ahalf * 16;
            *(int4*)(dh) = h0;
            *(int4*)(dh + 8) = h1;
            *(int4*)(dl) = l0;
            *(int4*)(dl + 8) = l1;
        }
        {
            const size_t go = (size_t)(n0 + brow) * K + kt + bchunk * 8;
            ushort* dh = sBh + brow * LDSW + bchunk * 8;
            ushort* dl = sBl + brow * LDSW + bchunk * 8;
            *(int4*)(dh) = *(const int4*)(BThi + go);
            *(int4*)(dl) = *(const int4*)(BTlo + go);
        }
        __syncthreads();

        bf16x8 ah[4], al[4], bh[2], bl[2];
#pragma unroll
        for (int mi = 0; mi < 4; mi++) {
            const int row = wm * 64 + mi * 16 + r16;
            ah[mi] = *(const bf16x8*)(sAh + row * LDSW + kg * 8);
            al[mi] = *(const bf16x8*)(sAl + row * LDSW + kg * 8);
        }
#pragma unroll
        for (int ni = 0; ni < 2; ni++) {
            const int row = wn * 32 + ni * 16 + r16;
            bh[ni] = *(const bf16x8*)(sBh + row * LDSW + kg * 8);
            bl[ni] = *(const bf16x8*)(sBl + row * LDSW + kg * 8);
        }
#pragma unroll
        for (int mi = 0; mi < 4; mi++)
#pragma unroll
            for (int ni = 0; ni < 2; ni++) {
                acc[mi][ni] = __builtin_amdgcn_mfma_f32_16x16x32_bf16(ah[mi], bh[ni], acc[mi][ni], 0, 0, 0);
                acc[mi][ni] = __builtin_amdgcn_mfma_f32_16x16x32_bf16(ah[mi], bl[ni], acc[mi][ni], 0, 0, 0);
                acc[mi][ni] = __builtin_amdgcn_mfma_f32_16x16x32_bf16(al[mi], bh[ni], acc[mi][ni], 0, 0, 0);
            }
        __syncthreads();
    }

    // epilogue: C/D mapping col=lane&15, row=(lane>>4)*4+reg  [m89-verified]
#pragma unroll
    for (int ni = 0; ni < 2; ni++) {
        const int col = n0 + wn * 32 + ni * 16 + r16;
        float bv = 0.f;
        if constexpr (MODE == 1) {
            bv = (col < nsplit && bias) ? bias[col] : 0.f;
        } else {
            bv = bias ? bias[col] : 0.f;
        }
#pragma unroll
        for (int mi = 0; mi < 4; mi++) {
#pragma unroll
            for (int r = 0; r < 4; r++) {
                const int row = m0 + wm * 64 + mi * 16 + kg * 4 + r;
                if (row >= M) continue;
                if constexpr (MODE == 1) {
                    const float v = acc[mi][ni][r];
                    if (col < nsplit) {
                        Cf[(size_t)row * nsplit + col] = v + bv;
                    } else {
                        Chi[(size_t)row * (Nc - nsplit) + (col - nsplit)] = f2bf_rne(v);
                    }
                } else {
                    float g = 1.f;
                    if (gate) g = (gate[row] > 0) ? 1.f : 0.f;
                    float v = acc[mi][ni][r] + bv * g;
                    if (relu) v = fmaxf(v, 0.f);
                    const size_t o = (size_t)row * Nc + col;
                    if constexpr (MODE == 0) {
                        Cf[o] = v;
                    } else {
                        ushort h, l;
                        split2(v, h, l);
                        Chi[o] = h;
                        Clo[o] = l;
                    }
                }
            }
        }
    }
}

// ---------------- CSR mean aggregation, column-slice passes ----------------
// One pass covers 64 features (qoff..qoff+63): resident Pbot line set = N*128B =
// 2.56MB -> fits per-XCD 4MB L2. Wave per node; lanes split: sub=lane>>5 picks
// edge parity, f=lane&31 picks feature pair. 8 load slots = 16 edges in flight.
// S = mean_e relu(Ptop[n](f32) + Pbot[src_e](bf16)), written as hi/lo bf16 slice.

template <int H>
__global__ __launch_bounds__(256) void agg_q(const float* __restrict__ Ptop,
                                             const ushort* __restrict__ Pbot,
                                             const int* __restrict__ row_ptr,
                                             const int* __restrict__ csr,
                                             ushort* __restrict__ Shi,
                                             ushort* __restrict__ Slo,
                                             int N, int qoff) {
    const int wave = threadIdx.x >> 6;
    const int lane = threadIdx.x & 63;
    const int n = blockIdx.x * 4 + wave;
    if (n >= N) return;

    const int sub = lane >> 5;  // edge parity handled by this half-wave
    const int f = lane & 31;    // feature-pair index within the 64-feature slice

    const int begin = row_ptr[n];
    const int end = row_ptr[n + 1];
    const int deg = end - begin;

    const float2 top = *(const float2*)(Ptop + (size_t)n * H + qoff + f * 2);
    float a0 = 0.f, a1 = 0.f;

    int e = begin;
    for (; e + 16 <= end; e += 16) {
        int idx[8];
#pragma unroll
        for (int j = 0; j < 8; j++) idx[j] = csr[e + 2 * j + sub];
        ushort2 v[8];
#pragma unroll
        for (int j = 0; j < 8; j++)
            v[j] = *(const ushort2*)(Pbot + (size_t)idx[j] * H + qoff + f * 2);
#pragma unroll
        for (int j = 0; j < 8; j++) {
            a0 += fmaxf(top.x + bf2f(v[j].x), 0.f);
            a1 += fmaxf(top.y + bf2f(v[j].y), 0.f);
        }
    }
    for (int t = e + sub; t < end; t += 2) {
        int s = csr[t];
        ushort2 v = *(const ushort2*)(Pbot + (size_t)s * H + qoff + f * 2);
        a0 += fmaxf(top.x + bf2f(v.x), 0.f);
        a1 += fmaxf(top.y + bf2f(v.y), 0.f);
    }

    // combine the two edge-parity halves
    a0 += __shfl_xor(a0, 32, 64);
    a1 += __shfl_xor(a1, 32, 64);

    if (sub == 0) {
        const float inv = (deg > 0) ? 1.f / (float)deg : 0.f;
        ushort2 h, l;
        split2(a0 * inv, h.x, l.x);
        split2(a1 * inv, h.y, l.y);
        *(ushort2*)(Shi + (size_t)n * H + qoff + f * 2) = h;
        *(ushort2*)(Slo + (size_t)n * H + qoff + f * 2) = l;
    }
}

// ---------------- launch ----------------

extern "C" void kernel_launch(void* const* d_in, const int* in_sizes, int n_in,
                              void* d_out, int out_size, void* d_ws, size_t ws_size,
                              hipStream_t stream) {
    const int N = in_sizes[0] / NODE_DIM;  // 20000
    const int E = in_sizes[1] / 2;         // 640000

    const float* x = (const float*)d_in[0];
    const int* ei = (const int*)d_in[1];
    const int* e_src = ei;
    const int* e_dst = ei + E;
    const float* W1a = (const float*)d_in[2];
    const float* b1a = (const float*)d_in[3];
    const float* W1b = (const float*)d_in[4];
    const float* b1b = (const float*)d_in[5];
    const float* W2a = (const float*)d_in[6];
    const float* b2a = (const float*)d_in[7];
    const float* W2b = (const float*)d_in[8];
    const float* b2b = (const float*)d_in[9];

    char* ws = (char*)d_ws;
    size_t off = 0;
    auto alloc = [&](size_t bytes) {
        size_t o = off;
        off += (bytes + 255) & ~(size_t)255;
        return o;
    };
    int* cnt = (int*)(ws + alloc((size_t)N * 4));
    int* row_ptr = (int*)(ws + alloc((size_t)(N + 1) * 4));
    int* cursor = (int*)(ws + alloc((size_t)N * 4));
    int* csr = (int*)(ws + alloc((size_t)E * 4));
    ushort* x_hi = (ushort*)(ws + alloc((size_t)N * NODE_DIM * 2));
    ushort* x_lo = (ushort*)(ws + alloc((size_t)N * NODE_DIM * 2));
    ushort* T1a_h = (ushort*)(ws + alloc((size_t)(2 * HID) * NODE_DIM * 2));  // [512][128]
    ushort* T1a_l = (ushort*)(ws + alloc((size_t)(2 * HID) * NODE_DIM * 2));
    ushort* T1b_h = (ushort*)(ws + alloc((size_t)HID * HID * 2));
    ushort* T1b_l = (ushort*)(ws + alloc((size_t)HID * HID * 2));
    ushort* T2a_h = (ushort*)(ws + alloc((size_t)(2 * OUTD) * HID * 2));  // [256][256]
    ushort* T2a_l = (ushort*)(ws + alloc((size_t)(2 * OUTD) * HID * 2));
    ushort* T2b_h = (ushort*)(ws + alloc((size_t)OUTD * OUTD * 2));
    ushort* T2b_l = (ushort*)(ws + alloc((size_t)OUTD * OUTD * 2));
    float* P1t = (float*)(ws + alloc((size_t)N * HID * 4));
    ushort* P1b = (ushort*)(ws + alloc((size_t)N * HID * 2));
    ushort* S1h = (ushort*)(ws + alloc((size_t)N * HID * 2));
    ushort* S1l = (ushort*)(ws + alloc((size_t)N * HID * 2));
    ushort* h_hi = (ushort*)(ws + alloc((size_t)N * HID * 2));
    ushort* h_lo = (ushort*)(ws + alloc((size_t)N * HID * 2));
    float* P2t = P1t;
    ushort* P2b = P1b;
    ushort* S2h = S1h;
    ushort* S2l = S1l;

    // CSR build
    zero_int_kernel<<<(N + 255) / 256, 256, 0, stream>>>(cnt, N);
    hist_kernel<<<(E + 255) / 256, 256, 0, stream>>>(e_dst, cnt, E);
    scan_kernel<<<1, 1024, 0, stream>>>(cnt, row_ptr, cursor, N);
    scatter_kernel<<<(E + 255) / 256, 256, 0, stream>>>(e_src, e_dst, cursor, csr, E);

    // input + weight prep
    split_kernel<<<((N * NODE_DIM / 4) + 255) / 256, 256, 0, stream>>>(x, x_hi, x_lo, N * NODE_DIM / 4);
    prep_weights<<<(212992 + 255) / 256, 256, 0, stream>>>(W1a, W1b, W2a, W2b,
                                                           T1a_h, T1a_l, T1b_h, T1b_l,
                                                           T2a_h, T2a_l, T2b_h, T2b_l);

    const int MT = (N + GBM - 1) / GBM;  // 157
    const int AB = (N + 3) / 4;          // agg blocks (4 nodes per block)

    // Layer 1: merged projection (Nc=512: [P1t f32+b1a | P1b bf16])
    gemm_bf3<1><<<dim3(MT, (2 * HID) / GBN), 256, 0, stream>>>(
        x_hi, x_lo, N, NODE_DIM, T1a_h, T1a_l, b1a, nullptr, 0,
        P1t, P1b, nullptr, 2 * HID, HID);
    for (int q = 0; q < HID / 64; q++)
        agg_q<HID><<<AB, 256, 0, stream>>>(P1t, P1b, row_ptr, csr, S1h, S1l, N, q * 64);
    gemm_bf3<2><<<dim3(MT, HID / GBN), 256, 0, stream>>>(
        S1h, S1l, N, HID, T1b_h, T1b_l, b1b, cnt, 1,
        nullptr, h_hi, h_lo, HID, 0);

    // Layer 2: merged projection (Nc=256: [P2t f32+b2a | P2b bf16])
    gemm_bf3<1><<<dim3(MT, (2 * OUTD) / GBN), 256, 0, stream>>>(
        h_hi, h_lo, N, HID, T2a_h, T2a_l, b2a, nullptr, 0,
        P2t, P2b, nullptr, 2 * OUTD, OUTD);
    for (int q = 0; q < OUTD / 64; q++)
        agg_q<OUTD><<<AB, 256, 0, stream>>>(P2t, P2b, row_ptr, csr, S2h, S2l, N, q * 64);
    gemm_bf3<0><<<dim3(MT, OUTD / GBN), 256, 0, stream>>>(
        S2h, S2l, N, OUTD, T2b_h, T2b_l, b2b, cnt, 0,
        (float*)d_out, nullptr, nullptr, OUTD, 0);
}

// Round 7
// 277.947 us; speedup vs baseline: 1.0671x; 1.0671x over previous
//
#include <hip/hip_runtime.h>
#include <hip/hip_bf16.h>

// GraphEncoder: 2-layer GNN, edge-MLP + scatter-mean.
//   cat(x_dst,x_src)@Wa = (x@Wa_top)[dst] + (x@Wa_bot)[src]
//   mean_agg(relu(pre)@Wb + bb) = mean_agg(relu(pre))@Wb + (cnt>0)*bb
// R7: agg = ONE dispatch/layer; 64-feat slice selected by XCD (blockIdx%8) for
//     per-XCD L2 residency (2.56MB<4MB); lane layout (fq=lane&15 x es=lane>>4)
//     gives 32 edges / 32 x 128B segments in flight per wave (2x R6).
//     split+weight-prep fused. 11 dispatches total (was 17).

#define NODE_DIM 128
#define HID 256
#define OUTD 128

typedef __attribute__((ext_vector_type(8))) short bf16x8;
typedef __attribute__((ext_vector_type(4))) float f32x4;

__device__ __forceinline__ float bf2f(ushort u) {
    return __uint_as_float(((unsigned)u) << 16);
}
__device__ __forceinline__ ushort f2bf_rne(float x) {
    unsigned u = __float_as_uint(x);
    unsigned r = u + 0x7fffu + ((u >> 16) & 1u);
    return (ushort)(r >> 16);
}
__device__ __forceinline__ void split2(float x, ushort& hi, ushort& lo) {
    hi = f2bf_rne(x);
    float hf = __uint_as_float(((unsigned)hi) << 16);
    lo = f2bf_rne(x - hf);
}

// ---------------- utility kernels ----------------

__global__ void zero_int_kernel(int* __restrict__ p, int n) {
    int i = blockIdx.x * blockDim.x + threadIdx.x;
    if (i < n) p[i] = 0;
}

__global__ void hist_kernel(const int* __restrict__ dst, int* __restrict__ cnt, int E) {
    int e = blockIdx.x * blockDim.x + threadIdx.x;
    if (e < E) atomicAdd(&cnt[dst[e]], 1);
}

// exclusive scan over cnt -> row_ptr + cursor; single block, shuffle-based
__global__ __launch_bounds__(1024) void scan_kernel(const int* __restrict__ cnt,
                                                    int* __restrict__ row_ptr,
                                                    int* __restrict__ cursor, int N) {
    __shared__ int wsum[16];
    const int tid = threadIdx.x;
    const int lane = tid & 63;
    const int wv = tid >> 6;
    int running = 0;
    for (int base = 0; base < N; base += 1024) {
        const int i = base + tid;
        const int v = (i < N) ? cnt[i] : 0;
        int x = v;
#pragma unroll
        for (int off = 1; off < 64; off <<= 1) {
            int t = __shfl_up(x, off, 64);
            if (lane >= off) x += t;
        }
        if (lane == 63) wsum[wv] = x;
        __syncthreads();
        if (wv == 0) {
            int s = (lane < 16) ? wsum[lane] : 0;
#pragma unroll
            for (int off = 1; off < 16; off <<= 1) {
                int t = __shfl_up(s, off, 64);
                if (lane >= off) s += t;
            }
            if (lane < 16) wsum[lane] = s;
        }
        __syncthreads();
        const int woff = (wv > 0) ? wsum[wv - 1] : 0;
        const int total = wsum[15];
        if (i < N) {
            int ex = running + woff + x - v;
            row_ptr[i] = ex;
            cursor[i] = ex;
        }
        running += total;
        __syncthreads();
    }
    if (tid == 0) row_ptr[N] = running;
}

__global__ void scatter_kernel(const int* __restrict__ src, const int* __restrict__ dst,
                               int* __restrict__ cursor, int* __restrict__ csr, int E) {
    int e = blockIdx.x * blockDim.x + threadIdx.x;
    if (e < E) {
        int p = atomicAdd(&cursor[dst[e]], 1);
        csr[p] = src[e];
    }
}

// Fused: x split (i < N*128/4, float4 granular) + all weight transposes/splits.
__global__ void prep_all(const float* __restrict__ x, int nx4,
                         ushort* __restrict__ x_hi, ushort* __restrict__ x_lo,
                         const float* __restrict__ W1a, const float* __restrict__ W1b,
                         const float* __restrict__ W2a, const float* __restrict__ W2b,
                         ushort* __restrict__ T1a_h, ushort* __restrict__ T1a_l,
                         ushort* __restrict__ T1b_h, ushort* __restrict__ T1b_l,
                         ushort* __restrict__ T2a_h, ushort* __restrict__ T2a_l,
                         ushort* __restrict__ T2b_h, ushort* __restrict__ T2b_l) {
    int i = blockIdx.x * blockDim.x + threadIdx.x;
    if (i < nx4) {
        float4 v = ((const float4*)x)[i];
        ushort4 h, l;
        split2(v.x, h.x, l.x);
        split2(v.y, h.y, l.y);
        split2(v.z, h.z, l.z);
        split2(v.w, h.w, l.w);
        ((ushort4*)x_hi)[i] = h;
        ((ushort4*)x_lo)[i] = l;
        return;
    }
    int j = i - nx4;
    float v;
    ushort *ph, *pl;
    int o;
    if (j < 65536) {  // T1a [n<512][k<128]; src W1a [256][256]
        int n = j >> 7, k = j & 127;
        v = (n < 256) ? W1a[k * 256 + n] : W1a[(128 + k) * 256 + (n - 256)];
        ph = T1a_h; pl = T1a_l; o = j;
    } else if (j < 131072) {  // T1b [n<256][k<256]; src W1b [256][256]
        int t = j - 65536;
        int n = t >> 8, k = t & 255;
        v = W1b[k * 256 + n];
        ph = T1b_h; pl = T1b_l; o = t;
    } else if (j < 196608) {  // T2a [n<256][k<256]; src W2a [512][128]
        int t = j - 131072;
        int n = t >> 8, k = t & 255;
        v = (n < 128) ? W2a[k * 128 + n] : W2a[(256 + k) * 128 + (n - 128)];
        ph = T2a_h; pl = T2a_l; o = t;
    } else if (j < 212992) {  // T2b [n<128][k<128]; src W2b [128][128]
        int t = j - 196608;
        int n = t >> 7, k = t & 127;
        v = W2b[k * 128 + n];
        ph = T2b_h; pl = T2b_l; o = t;
    } else {
        return;
    }
    ushort h, l;
    split2(v, h, l);
    ph[o] = h;
    pl[o] = l;
}

// ---------------- bf16 3-pass MFMA GEMM ----------------
// A[M][K] hi/lo bf16; B transposed [Nc][K] hi/lo. Tile BM=128,BN=64,BK=32; 4 waves.
// MODE 0: f32 out (+bias,+gate,+relu). MODE 1: dual — col<nsplit -> f32+bias;
// col>=nsplit -> bf16. MODE 2: hi/lo bf16 out (+bias,+gate,+relu).

#define GBM 128
#define GBN 64
#define GBK 32
#define LDSW 40

template <int MODE>
__global__ __launch_bounds__(256) void gemm_bf3(
    const ushort* __restrict__ Ahi, const ushort* __restrict__ Alo, int M, int K,
    const ushort* __restrict__ BThi, const ushort* __restrict__ BTlo,
    const float* __restrict__ bias, const int* __restrict__ gate, int relu,
    float* __restrict__ Cf, ushort* __restrict__ Chi, ushort* __restrict__ Clo,
    int Nc, int nsplit) {
    __shared__ ushort sAh[GBM * LDSW], sAl[GBM * LDSW];
    __shared__ ushort sBh[GBN * LDSW], sBl[GBN * LDSW];

    const int tid = threadIdx.x;
    const int lane = tid & 63;
    const int w = tid >> 6;
    const int wm = w >> 1, wn = w & 1;
    const int r16 = lane & 15, kg = lane >> 4;
    const int m0 = blockIdx.x * GBM;
    const int n0 = blockIdx.y * GBN;

    const int arow = tid >> 1, ahalf = tid & 1;   // A: 2 thr/row, 16 ushorts (2x int4)
    const int brow = tid >> 2, bchunk = tid & 3;  // B: 4 thr/row, 8 ushorts (1x int4)

    f32x4 acc[4][2];
#pragma unroll
    for (int i = 0; i < 4; i++)
#pragma unroll
        for (int j = 0; j < 2; j++) acc[i][j] = (f32x4)0.f;

    for (int kt = 0; kt < K; kt += GBK) {
        {
            const int gr = m0 + arow;
            int4 h0 = make_int4(0, 0, 0, 0), h1 = h0, l0 = h0, l1 = h0;
            if (gr < M) {
                const size_t go = (size_t)gr * K + kt + ahalf * 16;
                h0 = *(const int4*)(Ahi + go);
                h1 = *(const int4*)(Ahi + go + 8);
                l0 = *(const int4*)(Alo + go);
                l1 = *(const int4*)(Alo + go + 8);
            }
            ushort* dh = sAh + arow * LDSW + ahalf * 16;
            ushort* dl = sAl + arow * LDSW + ahalf * 16;
            *(int4*)(dh) = h0;
            *(int4*)(dh + 8) = h1;
            *(int4*)(dl) = l0;
            *(int4*)(dl + 8) = l1;
        }
        {
            const size_t go = (size_t)(n0 + brow) * K + kt + bchunk * 8;
            ushort* dh = sBh + brow * LDSW + bchunk * 8;
            ushort* dl = sBl + brow * LDSW + bchunk * 8;
            *(int4*)(dh) = *(const int4*)(BThi + go);
            *(int4*)(dl) = *(const int4*)(BTlo + go);
        }
        __syncthreads();

        bf16x8 ah[4], al[4], bh[2], bl[2];
#pragma unroll
        for (int mi = 0; mi < 4; mi++) {
            const int row = wm * 64 + mi * 16 + r16;
            ah[mi] = *(const bf16x8*)(sAh + row * LDSW + kg * 8);
            al[mi] = *(const bf16x8*)(sAl + row * LDSW + kg * 8);
        }
#pragma unroll
        for (int ni = 0; ni < 2; ni++) {
            const int row = wn * 32 + ni * 16 + r16;
            bh[ni] = *(const bf16x8*)(sBh + row * LDSW + kg * 8);
            bl[ni] = *(const bf16x8*)(sBl + row * LDSW + kg * 8);
        }
#pragma unroll
        for (int mi = 0; mi < 4; mi++)
#pragma unroll
            for (int ni = 0; ni < 2; ni++) {
                acc[mi][ni] = __builtin_amdgcn_mfma_f32_16x16x32_bf16(ah[mi], bh[ni], acc[mi][ni], 0, 0, 0);
                acc[mi][ni] = __builtin_amdgcn_mfma_f32_16x16x32_bf16(ah[mi], bl[ni], acc[mi][ni], 0, 0, 0);
                acc[mi][ni] = __builtin_amdgcn_mfma_f32_16x16x32_bf16(al[mi], bh[ni], acc[mi][ni], 0, 0, 0);
            }
        __syncthreads();
    }

    // epilogue: C/D mapping col=lane&15, row=(lane>>4)*4+reg  [m89-verified]
#pragma unroll
    for (int ni = 0; ni < 2; ni++) {
        const int col = n0 + wn * 32 + ni * 16 + r16;
        float bv = 0.f;
        if constexpr (MODE == 1) {
            bv = (col < nsplit && bias) ? bias[col] : 0.f;
        } else {
            bv = bias ? bias[col] : 0.f;
        }
#pragma unroll
        for (int mi = 0; mi < 4; mi++) {
#pragma unroll
            for (int r = 0; r < 4; r++) {
                const int row = m0 + wm * 64 + mi * 16 + kg * 4 + r;
                if (row >= M) continue;
                if constexpr (MODE == 1) {
                    const float v = acc[mi][ni][r];
                    if (col < nsplit) {
                        Cf[(size_t)row * nsplit + col] = v + bv;
                    } else {
                        Chi[(size_t)row * (Nc - nsplit) + (col - nsplit)] = f2bf_rne(v);
                    }
                } else {
                    float g = 1.f;
                    if (gate) g = (gate[row] > 0) ? 1.f : 0.f;
                    float v = acc[mi][ni][r] + bv * g;
                    if (relu) v = fmaxf(v, 0.f);
                    const size_t o = (size_t)row * Nc + col;
                    if constexpr (MODE == 0) {
                        Cf[o] = v;
                    } else {
                        ushort h, l;
                        split2(v, h, l);
                        Chi[o] = h;
                        Clo[o] = l;
                    }
                }
            }
        }
    }
}

// ---------------- CSR mean aggregation, XCD-sliced, single dispatch ----------------
// Slice (64 feats) chosen by XCD (= blockIdx%8): per-XCD resident Pbot line set is
// N*128B = 2.56MB < 4MB L2. Wave per node. Lanes: fq=lane&15 feature-quad (ushort4),
// es=lane>>4 edge select; each load inst covers 4 edges (4 x 128B segments); 8 slots
// = 32 edges / 32 segments in flight. shfl_xor(16,32) combines edge groups.
// S = mean_e relu(Ptop[n](f32) + Pbot[src_e](bf16)) -> hi/lo bf16 slice.

template <int H>
__global__ __launch_bounds__(256) void agg_x(const float* __restrict__ Ptop,
                                             const ushort* __restrict__ Pbot,
                                             const int* __restrict__ row_ptr,
                                             const int* __restrict__ csr,
                                             ushort* __restrict__ Shi,
                                             ushort* __restrict__ Slo, int N) {
    constexpr int SLICES = H / 64;
    constexpr int XPS = 8 / SLICES;  // XCDs per slice

    const int bid = blockIdx.x;
    const int xcd = bid & 7;
    const int grp = bid >> 3;
    const int slice = xcd / XPS;
    const int subx = xcd % XPS;
    const int wave = threadIdx.x >> 6;
    const int lane = threadIdx.x & 63;

    const int n = (grp * XPS + subx) * 4 + wave;
    if (n >= N) return;
    const int qoff = slice * 64;

    const int fq = lane & 15;  // feature quad (4 feats, 8B)
    const int es = lane >> 4;  // edge-select 0..3

    const int begin = row_ptr[n];
    const int end = row_ptr[n + 1];
    const int deg = end - begin;

    const float4 top = *(const float4*)(Ptop + (size_t)n * H + qoff + fq * 4);
    float a0 = 0.f, a1 = 0.f, a2 = 0.f, a3 = 0.f;

    int e = begin;
    for (; e + 32 <= end; e += 32) {
        int idx[8];
#pragma unroll
        for (int j = 0; j < 8; j++) idx[j] = csr[e + j * 4 + es];
        ushort4 v[8];
#pragma unroll
        for (int j = 0; j < 8; j++)
            v[j] = *(const ushort4*)(Pbot + (size_t)idx[j] * H + qoff + fq * 4);
#pragma unroll
        for (int j = 0; j < 8; j++) {
            a0 += fmaxf(top.x + bf2f(v[j].x), 0.f);
            a1 += fmaxf(top.y + bf2f(v[j].y), 0.f);
            a2 += fmaxf(top.z + bf2f(v[j].z), 0.f);
            a3 += fmaxf(top.w + bf2f(v[j].w), 0.f);
        }
    }
    for (int t = e + es; t < end; t += 4) {
        int s = csr[t];
        ushort4 v = *(const ushort4*)(Pbot + (size_t)s * H + qoff + fq * 4);
        a0 += fmaxf(top.x + bf2f(v.x), 0.f);
        a1 += fmaxf(top.y + bf2f(v.y), 0.f);
        a2 += fmaxf(top.z + bf2f(v.z), 0.f);
        a3 += fmaxf(top.w + bf2f(v.w), 0.f);
    }

    // combine the 4 edge groups (lanes differing in bits 4,5)
    a0 += __shfl_xor(a0, 16, 64);
    a1 += __shfl_xor(a1, 16, 64);
    a2 += __shfl_xor(a2, 16, 64);
    a3 += __shfl_xor(a3, 16, 64);
    a0 += __shfl_xor(a0, 32, 64);
    a1 += __shfl_xor(a1, 32, 64);
    a2 += __shfl_xor(a2, 32, 64);
    a3 += __shfl_xor(a3, 32, 64);

    if (es == 0) {
        const float inv = (deg > 0) ? 1.f / (float)deg : 0.f;
        ushort4 h, l;
        split2(a0 * inv, h.x, l.x);
        split2(a1 * inv, h.y, l.y);
        split2(a2 * inv, h.z, l.z);
        split2(a3 * inv, h.w, l.w);
        *(ushort4*)(Shi + (size_t)n * H + qoff + fq * 4) = h;
        *(ushort4*)(Slo + (size_t)n * H + qoff + fq * 4) = l;
    }
}

// ---------------- launch ----------------

extern "C" void kernel_launch(void* const* d_in, const int* in_sizes, int n_in,
                              void* d_out, int out_size, void* d_ws, size_t ws_size,
                              hipStream_t stream) {
    const int N = in_sizes[0] / NODE_DIM;  // 20000
    const int E = in_sizes[1] / 2;         // 640000

    const float* x = (const float*)d_in[0];
    const int* ei = (const int*)d_in[1];
    const int* e_src = ei;
    const int* e_dst = ei + E;
    const float* W1a = (const float*)d_in[2];
    const float* b1a = (const float*)d_in[3];
    const float* W1b = (const float*)d_in[4];
    const float* b1b = (const float*)d_in[5];
    const float* W2a = (const float*)d_in[6];
    const float* b2a = (const float*)d_in[7];
    const float* W2b = (const float*)d_in[8];
    const float* b2b = (const float*)d_in[9];

    char* ws = (char*)d_ws;
    size_t off = 0;
    auto alloc = [&](size_t bytes) {
        size_t o = off;
        off += (bytes + 255) & ~(size_t)255;
        return o;
    };
    int* cnt = (int*)(ws + alloc((size_t)N * 4));
    int* row_ptr = (int*)(ws + alloc((size_t)(N + 1) * 4));
    int* cursor = (int*)(ws + alloc((size_t)N * 4));
    int* csr = (int*)(ws + alloc((size_t)E * 4));
    ushort* x_hi = (ushort*)(ws + alloc((size_t)N * NODE_DIM * 2));
    ushort* x_lo = (ushort*)(ws + alloc((size_t)N * NODE_DIM * 2));
    ushort* T1a_h = (ushort*)(ws + alloc((size_t)(2 * HID) * NODE_DIM * 2));  // [512][128]
    ushort* T1a_l = (ushort*)(ws + alloc((size_t)(2 * HID) * NODE_DIM * 2));
    ushort* T1b_h = (ushort*)(ws + alloc((size_t)HID * HID * 2));
    ushort* T1b_l = (ushort*)(ws + alloc((size_t)HID * HID * 2));
    ushort* T2a_h = (ushort*)(ws + alloc((size_t)(2 * OUTD) * HID * 2));  // [256][256]
    ushort* T2a_l = (ushort*)(ws + alloc((size_t)(2 * OUTD) * HID * 2));
    ushort* T2b_h = (ushort*)(ws + alloc((size_t)OUTD * OUTD * 2));
    ushort* T2b_l = (ushort*)(ws + alloc((size_t)OUTD * OUTD * 2));
    float* P1t = (float*)(ws + alloc((size_t)N * HID * 4));
    ushort* P1b = (ushort*)(ws + alloc((size_t)N * HID * 2));
    ushort* S1h = (ushort*)(ws + alloc((size_t)N * HID * 2));
    ushort* S1l = (ushort*)(ws + alloc((size_t)N * HID * 2));
    ushort* h_hi = (ushort*)(ws + alloc((size_t)N * HID * 2));
    ushort* h_lo = (ushort*)(ws + alloc((size_t)N * HID * 2));
    float* P2t = P1t;
    ushort* P2b = P1b;
    ushort* S2h = S1h;
    ushort* S2l = S1l;

    // CSR build
    zero_int_kernel<<<(N + 255) / 256, 256, 0, stream>>>(cnt, N);
    hist_kernel<<<(E + 255) / 256, 256, 0, stream>>>(e_dst, cnt, E);
    scan_kernel<<<1, 1024, 0, stream>>>(cnt, row_ptr, cursor, N);
    scatter_kernel<<<(E + 255) / 256, 256, 0, stream>>>(e_src, e_dst, cursor, csr, E);

    // fused input/weight prep
    const int nx4 = N * NODE_DIM / 4;
    prep_all<<<(nx4 + 212992 + 255) / 256, 256, 0, stream>>>(
        x, nx4, x_hi, x_lo, W1a, W1b, W2a, W2b,
        T1a_h, T1a_l, T1b_h, T1b_l, T2a_h, T2a_l, T2b_h, T2b_l);

    const int MT = (N + GBM - 1) / GBM;  // 157
    // agg grids: 8 * ceil(N / (4 * XPS)), XPS = 8/(H/64)
    const int AB1 = 8 * ((N + 4 * 2 - 1) / (4 * 2));  // H=256: XPS=2 -> 20000
    const int AB2 = 8 * ((N + 4 * 4 - 1) / (4 * 4));  // H=128: XPS=4 -> 10000

    // Layer 1: merged projection (Nc=512: [P1t f32+b1a | P1b bf16])
    gemm_bf3<1><<<dim3(MT, (2 * HID) / GBN), 256, 0, stream>>>(
        x_hi, x_lo, N, NODE_DIM, T1a_h, T1a_l, b1a, nullptr, 0,
        P1t, P1b, nullptr, 2 * HID, HID);
    agg_x<HID><<<AB1, 256, 0, stream>>>(P1t, P1b, row_ptr, csr, S1h, S1l, N);
    gemm_bf3<2><<<dim3(MT, HID / GBN), 256, 0, stream>>>(
        S1h, S1l, N, HID, T1b_h, T1b_l, b1b, cnt, 1,
        nullptr, h_hi, h_lo, HID, 0);

    // Layer 2: merged projection (Nc=256: [P2t f32+b2a | P2b bf16])
    gemm_bf3<1><<<dim3(MT, (2 * OUTD) / GBN), 256, 0, stream>>>(
        h_hi, h_lo, N, HID, T2a_h, T2a_l, b2a, nullptr, 0,
        P2t, P2b, nullptr, 2 * OUTD, OUTD);
    agg_x<OUTD><<<AB2, 256, 0, stream>>>(P2t, P2b, row_ptr, csr, S2h, S2l, N);
    gemm_bf3<0><<<dim3(MT, OUTD / GBN), 256, 0, stream>>>(
        S2h, S2l, N, OUTD, T2b_h, T2b_l, b2b, cnt, 0,
        (float*)d_out, nullptr, nullptr, OUTD, 0);
}

// Round 8
// 268.889 us; speedup vs baseline: 1.1031x; 1.0337x over previous
//
#include <hip/hip_runtime.h>
#include <hip/hip_bf16.h>

// GraphEncoder: 2-layer GNN, edge-MLP + scatter-mean.
//   cat(x_dst,x_src)@Wa = (x@Wa_top)[dst] + (x@Wa_bot)[src]
//   mean_agg(relu(pre)@Wb + bb) = mean_agg(relu(pre))@Wb + (cnt>0)*bb
// R8: agg keeps R7's XCD-sliced L2 residency (FETCH 120->29MB confirmed) but the
//     edge loop is now a single PREDICATED 32-edge batch (clamped idx + 0/1 mask
//     fma) — R7's serial remainder tail (avg ~16 one-load-latency iterations for
//     deg%32) was the 60us cost.

#define NODE_DIM 128
#define HID 256
#define OUTD 128

typedef __attribute__((ext_vector_type(8))) short bf16x8;
typedef __attribute__((ext_vector_type(4))) float f32x4;

__device__ __forceinline__ float bf2f(ushort u) {
    return __uint_as_float(((unsigned)u) << 16);
}
__device__ __forceinline__ ushort f2bf_rne(float x) {
    unsigned u = __float_as_uint(x);
    unsigned r = u + 0x7fffu + ((u >> 16) & 1u);
    return (ushort)(r >> 16);
}
__device__ __forceinline__ void split2(float x, ushort& hi, ushort& lo) {
    hi = f2bf_rne(x);
    float hf = __uint_as_float(((unsigned)hi) << 16);
    lo = f2bf_rne(x - hf);
}

// ---------------- utility kernels ----------------

__global__ void zero_int_kernel(int* __restrict__ p, int n) {
    int i = blockIdx.x * blockDim.x + threadIdx.x;
    if (i < n) p[i] = 0;
}

__global__ void hist_kernel(const int* __restrict__ dst, int* __restrict__ cnt, int E) {
    int e = blockIdx.x * blockDim.x + threadIdx.x;
    if (e < E) atomicAdd(&cnt[dst[e]], 1);
}

// exclusive scan over cnt -> row_ptr + cursor; single block, shuffle-based
__global__ __launch_bounds__(1024) void scan_kernel(const int* __restrict__ cnt,
                                                    int* __restrict__ row_ptr,
                                                    int* __restrict__ cursor, int N) {
    __shared__ int wsum[16];
    const int tid = threadIdx.x;
    const int lane = tid & 63;
    const int wv = tid >> 6;
    int running = 0;
    for (int base = 0; base < N; base += 1024) {
        const int i = base + tid;
        const int v = (i < N) ? cnt[i] : 0;
        int x = v;
#pragma unroll
        for (int off = 1; off < 64; off <<= 1) {
            int t = __shfl_up(x, off, 64);
            if (lane >= off) x += t;
        }
        if (lane == 63) wsum[wv] = x;
        __syncthreads();
        if (wv == 0) {
            int s = (lane < 16) ? wsum[lane] : 0;
#pragma unroll
            for (int off = 1; off < 16; off <<= 1) {
                int t = __shfl_up(s, off, 64);
                if (lane >= off) s += t;
            }
            if (lane < 16) wsum[lane] = s;
        }
        __syncthreads();
        const int woff = (wv > 0) ? wsum[wv - 1] : 0;
        const int total = wsum[15];
        if (i < N) {
            int ex = running + woff + x - v;
            row_ptr[i] = ex;
            cursor[i] = ex;
        }
        running += total;
        __syncthreads();
    }
    if (tid == 0) row_ptr[N] = running;
}

__global__ void scatter_kernel(const int* __restrict__ src, const int* __restrict__ dst,
                               int* __restrict__ cursor, int* __restrict__ csr, int E) {
    int e = blockIdx.x * blockDim.x + threadIdx.x;
    if (e < E) {
        int p = atomicAdd(&cursor[dst[e]], 1);
        csr[p] = src[e];
    }
}

// Fused: x split (i < N*128/4, float4 granular) + all weight transposes/splits.
__global__ void prep_all(const float* __restrict__ x, int nx4,
                         ushort* __restrict__ x_hi, ushort* __restrict__ x_lo,
                         const float* __restrict__ W1a, const float* __restrict__ W1b,
                         const float* __restrict__ W2a, const float* __restrict__ W2b,
                         ushort* __restrict__ T1a_h, ushort* __restrict__ T1a_l,
                         ushort* __restrict__ T1b_h, ushort* __restrict__ T1b_l,
                         ushort* __restrict__ T2a_h, ushort* __restrict__ T2a_l,
                         ushort* __restrict__ T2b_h, ushort* __restrict__ T2b_l) {
    int i = blockIdx.x * blockDim.x + threadIdx.x;
    if (i < nx4) {
        float4 v = ((const float4*)x)[i];
        ushort4 h, l;
        split2(v.x, h.x, l.x);
        split2(v.y, h.y, l.y);
        split2(v.z, h.z, l.z);
        split2(v.w, h.w, l.w);
        ((ushort4*)x_hi)[i] = h;
        ((ushort4*)x_lo)[i] = l;
        return;
    }
    int j = i - nx4;
    float v;
    ushort *ph, *pl;
    int o;
    if (j < 65536) {  // T1a [n<512][k<128]; src W1a [256][256]
        int n = j >> 7, k = j & 127;
        v = (n < 256) ? W1a[k * 256 + n] : W1a[(128 + k) * 256 + (n - 256)];
        ph = T1a_h; pl = T1a_l; o = j;
    } else if (j < 131072) {  // T1b [n<256][k<256]; src W1b [256][256]
        int t = j - 65536;
        int n = t >> 8, k = t & 255;
        v = W1b[k * 256 + n];
        ph = T1b_h; pl = T1b_l; o = t;
    } else if (j < 196608) {  // T2a [n<256][k<256]; src W2a [512][128]
        int t = j - 131072;
        int n = t >> 8, k = t & 255;
        v = (n < 128) ? W2a[k * 128 + n] : W2a[(256 + k) * 128 + (n - 128)];
        ph = T2a_h; pl = T2a_l; o = t;
    } else if (j < 212992) {  // T2b [n<128][k<128]; src W2b [128][128]
        int t = j - 196608;
        int n = t >> 7, k = t & 127;
        v = W2b[k * 128 + n];
        ph = T2b_h; pl = T2b_l; o = t;
    } else {
        return;
    }
    ushort h, l;
    split2(v, h, l);
    ph[o] = h;
    pl[o] = l;
}

// ---------------- bf16 3-pass MFMA GEMM ----------------
// A[M][K] hi/lo bf16; B transposed [Nc][K] hi/lo. Tile BM=128,BN=64,BK=32; 4 waves.
// MODE 0: f32 out (+bias,+gate,+relu). MODE 1: dual — col<nsplit -> f32+bias;
// col>=nsplit -> bf16. MODE 2: hi/lo bf16 out (+bias,+gate,+relu).

#define GBM 128
#define GBN 64
#define GBK 32
#define LDSW 40

template <int MODE>
__global__ __launch_bounds__(256) void gemm_bf3(
    const ushort* __restrict__ Ahi, const ushort* __restrict__ Alo, int M, int K,
    const ushort* __restrict__ BThi, const ushort* __restrict__ BTlo,
    const float* __restrict__ bias, const int* __restrict__ gate, int relu,
    float* __restrict__ Cf, ushort* __restrict__ Chi, ushort* __restrict__ Clo,
    int Nc, int nsplit) {
    __shared__ ushort sAh[GBM * LDSW], sAl[GBM * LDSW];
    __shared__ ushort sBh[GBN * LDSW], sBl[GBN * LDSW];

    const int tid = threadIdx.x;
    const int lane = tid & 63;
    const int w = tid >> 6;
    const int wm = w >> 1, wn = w & 1;
    const int r16 = lane & 15, kg = lane >> 4;
    const int m0 = blockIdx.x * GBM;
    const int n0 = blockIdx.y * GBN;

    const int arow = tid >> 1, ahalf = tid & 1;   // A: 2 thr/row, 16 ushorts (2x int4)
    const int brow = tid >> 2, bchunk = tid & 3;  // B: 4 thr/row, 8 ushorts (1x int4)

    f32x4 acc[4][2];
#pragma unroll
    for (int i = 0; i < 4; i++)
#pragma unroll
        for (int j = 0; j < 2; j++) acc[i][j] = (f32x4)0.f;

    for (int kt = 0; kt < K; kt += GBK) {
        {
            const int gr = m0 + arow;
            int4 h0 = make_int4(0, 0, 0, 0), h1 = h0, l0 = h0, l1 = h0;
            if (gr < M) {
                const size_t go = (size_t)gr * K + kt + ahalf * 16;
                h0 = *(const int4*)(Ahi + go);
                h1 = *(const int4*)(Ahi + go + 8);
                l0 = *(const int4*)(Alo + go);
                l1 = *(const int4*)(Alo + go + 8);
            }
            ushort* dh = sAh + arow * LDSW + ahalf * 16;
            ushort* dl = sAl + arow * LDSW + ahalf * 16;
            *(int4*)(dh) = h0;
            *(int4*)(dh + 8) = h1;
            *(int4*)(dl) = l0;
            *(int4*)(dl + 8) = l1;
        }
        {
            const size_t go = (size_t)(n0 + brow) * K + kt + bchunk * 8;
            ushort* dh = sBh + brow * LDSW + bchunk * 8;
            ushort* dl = sBl + brow * LDSW + bchunk * 8;
            *(int4*)(dh) = *(const int4*)(BThi + go);
            *(int4*)(dl) = *(const int4*)(BTlo + go);
        }
        __syncthreads();

        bf16x8 ah[4], al[4], bh[2], bl[2];
#pragma unroll
        for (int mi = 0; mi < 4; mi++) {
            const int row = wm * 64 + mi * 16 + r16;
            ah[mi] = *(const bf16x8*)(sAh + row * LDSW + kg * 8);
            al[mi] = *(const bf16x8*)(sAl + row * LDSW + kg * 8);
        }
#pragma unroll
        for (int ni = 0; ni < 2; ni++) {
            const int row = wn * 32 + ni * 16 + r16;
            bh[ni] = *(const bf16x8*)(sBh + row * LDSW + kg * 8);
            bl[ni] = *(const bf16x8*)(sBl + row * LDSW + kg * 8);
        }
#pragma unroll
        for (int mi = 0; mi < 4; mi++)
#pragma unroll
            for (int ni = 0; ni < 2; ni++) {
                acc[mi][ni] = __builtin_amdgcn_mfma_f32_16x16x32_bf16(ah[mi], bh[ni], acc[mi][ni], 0, 0, 0);
                acc[mi][ni] = __builtin_amdgcn_mfma_f32_16x16x32_bf16(ah[mi], bl[ni], acc[mi][ni], 0, 0, 0);
                acc[mi][ni] = __builtin_amdgcn_mfma_f32_16x16x32_bf16(al[mi], bh[ni], acc[mi][ni], 0, 0, 0);
            }
        __syncthreads();
    }

    // epilogue: C/D mapping col=lane&15, row=(lane>>4)*4+reg  [m89-verified]
#pragma unroll
    for (int ni = 0; ni < 2; ni++) {
        const int col = n0 + wn * 32 + ni * 16 + r16;
        float bv = 0.f;
        if constexpr (MODE == 1) {
            bv = (col < nsplit && bias) ? bias[col] : 0.f;
        } else {
            bv = bias ? bias[col] : 0.f;
        }
#pragma unroll
        for (int mi = 0; mi < 4; mi++) {
#pragma unroll
            for (int r = 0; r < 4; r++) {
                const int row = m0 + wm * 64 + mi * 16 + kg * 4 + r;
                if (row >= M) continue;
                if constexpr (MODE == 1) {
                    const float v = acc[mi][ni][r];
                    if (col < nsplit) {
                        Cf[(size_t)row * nsplit + col] = v + bv;
                    } else {
                        Chi[(size_t)row * (Nc - nsplit) + (col - nsplit)] = f2bf_rne(v);
                    }
                } else {
                    float g = 1.f;
                    if (gate) g = (gate[row] > 0) ? 1.f : 0.f;
                    float v = acc[mi][ni][r] + bv * g;
                    if (relu) v = fmaxf(v, 0.f);
                    const size_t o = (size_t)row * Nc + col;
                    if constexpr (MODE == 0) {
                        Cf[o] = v;
                    } else {
                        ushort h, l;
                        split2(v, h, l);
                        Chi[o] = h;
                        Clo[o] = l;
                    }
                }
            }
        }
    }
}

// ---------------- CSR mean aggregation, XCD-sliced, predicated batch ----------------
// Slice (64 feats) via blockIdx%8 -> per-XCD resident Pbot set 2.56MB < 4MB L2.
// Wave per node-slice. fq=lane&15 (ushort4 feats), es=lane>>4 (edge group).
// Every iteration: 8 slots x 4 edges, clamped idx + 0/1 mask fma. No serial tail.

template <int H>
__global__ __launch_bounds__(256) void agg_x(const float* __restrict__ Ptop,
                                             const ushort* __restrict__ Pbot,
                                             const int* __restrict__ row_ptr,
                                             const int* __restrict__ csr,
                                             ushort* __restrict__ Shi,
                                             ushort* __restrict__ Slo, int N) {
    constexpr int SLICES = H / 64;
    constexpr int XPS = 8 / SLICES;  // XCDs per slice

    const int bid = blockIdx.x;
    const int xcd = bid & 7;
    const int grp = bid >> 3;
    const int slice = xcd / XPS;
    const int subx = xcd % XPS;
    const int wave = threadIdx.x >> 6;
    const int lane = threadIdx.x & 63;

    const int n = (grp * XPS + subx) * 4 + wave;
    if (n >= N) return;
    const int qoff = slice * 64;

    const int fq = lane & 15;  // feature quad (4 feats, 8B)
    const int es = lane >> 4;  // edge group 0..3

    const int begin = row_ptr[n];
    const int end = row_ptr[n + 1];
    const int deg = end - begin;

    const float4 top = *(const float4*)(Ptop + (size_t)n * H + qoff + fq * 4);
    float a0 = 0.f, a1 = 0.f, a2 = 0.f, a3 = 0.f;

    for (int e = begin; e < end; e += 32) {
        int idx[8];
        float m[8];
#pragma unroll
        for (int j = 0; j < 8; j++) {
            const int t = e + j * 4 + es;
            const bool valid = t < end;
            idx[j] = csr[valid ? t : begin];
            m[j] = valid ? 1.f : 0.f;
        }
        ushort4 v[8];
#pragma unroll
        for (int j = 0; j < 8; j++)
            v[j] = *(const ushort4*)(Pbot + (size_t)idx[j] * H + qoff + fq * 4);
#pragma unroll
        for (int j = 0; j < 8; j++) {
            a0 = fmaf(m[j], fmaxf(top.x + bf2f(v[j].x), 0.f), a0);
            a1 = fmaf(m[j], fmaxf(top.y + bf2f(v[j].y), 0.f), a1);
            a2 = fmaf(m[j], fmaxf(top.z + bf2f(v[j].z), 0.f), a2);
            a3 = fmaf(m[j], fmaxf(top.w + bf2f(v[j].w), 0.f), a3);
        }
    }

    // combine the 4 edge groups (lanes differing in bits 4,5)
    a0 += __shfl_xor(a0, 16, 64);
    a1 += __shfl_xor(a1, 16, 64);
    a2 += __shfl_xor(a2, 16, 64);
    a3 += __shfl_xor(a3, 16, 64);
    a0 += __shfl_xor(a0, 32, 64);
    a1 += __shfl_xor(a1, 32, 64);
    a2 += __shfl_xor(a2, 32, 64);
    a3 += __shfl_xor(a3, 32, 64);

    if (es == 0) {
        const float inv = (deg > 0) ? 1.f / (float)deg : 0.f;
        ushort4 h, l;
        split2(a0 * inv, h.x, l.x);
        split2(a1 * inv, h.y, l.y);
        split2(a2 * inv, h.z, l.z);
        split2(a3 * inv, h.w, l.w);
        *(ushort4*)(Shi + (size_t)n * H + qoff + fq * 4) = h;
        *(ushort4*)(Slo + (size_t)n * H + qoff + fq * 4) = l;
    }
}

// ---------------- launch ----------------

extern "C" void kernel_launch(void* const* d_in, const int* in_sizes, int n_in,
                              void* d_out, int out_size, void* d_ws, size_t ws_size,
                              hipStream_t stream) {
    const int N = in_sizes[0] / NODE_DIM;  // 20000
    const int E = in_sizes[1] / 2;         // 640000

    const float* x = (const float*)d_in[0];
    const int* ei = (const int*)d_in[1];
    const int* e_src = ei;
    const int* e_dst = ei + E;
    const float* W1a = (const float*)d_in[2];
    const float* b1a = (const float*)d_in[3];
    const float* W1b = (const float*)d_in[4];
    const float* b1b = (const float*)d_in[5];
    const float* W2a = (const float*)d_in[6];
    const float* b2a = (const float*)d_in[7];
    const float* W2b = (const float*)d_in[8];
    const float* b2b = (const float*)d_in[9];

    char* ws = (char*)d_ws;
    size_t off = 0;
    auto alloc = [&](size_t bytes) {
        size_t o = off;
        off += (bytes + 255) & ~(size_t)255;
        return o;
    };
    int* cnt = (int*)(ws + alloc((size_t)N * 4));
    int* row_ptr = (int*)(ws + alloc((size_t)(N + 1) * 4));
    int* cursor = (int*)(ws + alloc((size_t)N * 4));
    int* csr = (int*)(ws + alloc((size_t)E * 4));
    ushort* x_hi = (ushort*)(ws + alloc((size_t)N * NODE_DIM * 2));
    ushort* x_lo = (ushort*)(ws + alloc((size_t)N * NODE_DIM * 2));
    ushort* T1a_h = (ushort*)(ws + alloc((size_t)(2 * HID) * NODE_DIM * 2));  // [512][128]
    ushort* T1a_l = (ushort*)(ws + alloc((size_t)(2 * HID) * NODE_DIM * 2));
    ushort* T1b_h = (ushort*)(ws + alloc((size_t)HID * HID * 2));
    ushort* T1b_l = (ushort*)(ws + alloc((size_t)HID * HID * 2));
    ushort* T2a_h = (ushort*)(ws + alloc((size_t)(2 * OUTD) * HID * 2));  // [256][256]
    ushort* T2a_l = (ushort*)(ws + alloc((size_t)(2 * OUTD) * HID * 2));
    ushort* T2b_h = (ushort*)(ws + alloc((size_t)OUTD * OUTD * 2));
    ushort* T2b_l = (ushort*)(ws + alloc((size_t)OUTD * OUTD * 2));
    float* P1t = (float*)(ws + alloc((size_t)N * HID * 4));
    ushort* P1b = (ushort*)(ws + alloc((size_t)N * HID * 2));
    ushort* S1h = (ushort*)(ws + alloc((size_t)N * HID * 2));
    ushort* S1l = (ushort*)(ws + alloc((size_t)N * HID * 2));
    ushort* h_hi = (ushort*)(ws + alloc((size_t)N * HID * 2));
    ushort* h_lo = (ushort*)(ws + alloc((size_t)N * HID * 2));
    float* P2t = P1t;
    ushort* P2b = P1b;
    ushort* S2h = S1h;
    ushort* S2l = S1l;

    // CSR build
    zero_int_kernel<<<(N + 255) / 256, 256, 0, stream>>>(cnt, N);
    hist_kernel<<<(E + 255) / 256, 256, 0, stream>>>(e_dst, cnt, E);
    scan_kernel<<<1, 1024, 0, stream>>>(cnt, row_ptr, cursor, N);
    scatter_kernel<<<(E + 255) / 256, 256, 0, stream>>>(e_src, e_dst, cursor, csr, E);

    // fused input/weight prep
    const int nx4 = N * NODE_DIM / 4;
    prep_all<<<(nx4 + 212992 + 255) / 256, 256, 0, stream>>>(
        x, nx4, x_hi, x_lo, W1a, W1b, W2a, W2b,
        T1a_h, T1a_l, T1b_h, T1b_l, T2a_h, T2a_l, T2b_h, T2b_l);

    const int MT = (N + GBM - 1) / GBM;  // 157
    // agg grids: 8 * ceil(N / (4 * XPS)), XPS = 8/(H/64)
    const int AB1 = 8 * ((N + 4 * 2 - 1) / (4 * 2));  // H=256: XPS=2 -> 20000
    const int AB2 = 8 * ((N + 4 * 4 - 1) / (4 * 4));  // H=128: XPS=4 -> 10000

    // Layer 1: merged projection (Nc=512: [P1t f32+b1a | P1b bf16])
    gemm_bf3<1><<<dim3(MT, (2 * HID) / GBN), 256, 0, stream>>>(
        x_hi, x_lo, N, NODE_DIM, T1a_h, T1a_l, b1a, nullptr, 0,
        P1t, P1b, nullptr, 2 * HID, HID);
    agg_x<HID><<<AB1, 256, 0, stream>>>(P1t, P1b, row_ptr, csr, S1h, S1l, N);
    gemm_bf3<2><<<dim3(MT, HID / GBN), 256, 0, stream>>>(
        S1h, S1l, N, HID, T1b_h, T1b_l, b1b, cnt, 1,
        nullptr, h_hi, h_lo, HID, 0);

    // Layer 2: merged projection (Nc=256: [P2t f32+b2a | P2b bf16])
    gemm_bf3<1><<<dim3(MT, (2 * OUTD) / GBN), 256, 0, stream>>>(
        h_hi, h_lo, N, HID, T2a_h, T2a_l, b2a, nullptr, 0,
        P2t, P2b, nullptr, 2 * OUTD, OUTD);
    agg_x<OUTD><<<AB2, 256, 0, stream>>>(P2t, P2b, row_ptr, csr, S2h, S2l, N);
    gemm_bf3<0><<<dim3(MT, OUTD / GBN), 256, 0, stream>>>(
        S2h, S2l, N, OUTD, T2b_h, T2b_l, b2b, cnt, 0,
        (float*)d_out, nullptr, nullptr, OUTD, 0);
}

// Round 9
// 249.583 us; speedup vs baseline: 1.1884x; 1.0774x over previous
//
#include <hip/hip_runtime.h>
#include <hip/hip_bf16.h>

// GraphEncoder: 2-layer GNN, edge-MLP + scatter-mean.
//   cat(x_dst,x_src)@Wa = (x@Wa_top)[dst] + (x@Wa_bot)[src]
//   mean_agg(relu(pre)@Wb + bb) = mean_agg(relu(pre))@Wb + (cnt>0)*bb
// R9: selective precision — 3-pass Ootomo only at the chain ends (x-projection,
//     final GEMM); middle GEMMs plain 1-pass bf16 (S1/h single-bf16).
//     Agg: unpredicated body for full 32-edge blocks + ONE predicated tail
//     iteration (R8 showed VALU-issue-bound at 87% — cut clamp/mask ops).

#define NODE_DIM 128
#define HID 256
#define OUTD 128

typedef __attribute__((ext_vector_type(8))) short bf16x8;
typedef __attribute__((ext_vector_type(4))) float f32x4;

__device__ __forceinline__ float bf2f(ushort u) {
    return __uint_as_float(((unsigned)u) << 16);
}
__device__ __forceinline__ ushort f2bf_rne(float x) {
    unsigned u = __float_as_uint(x);
    unsigned r = u + 0x7fffu + ((u >> 16) & 1u);
    return (ushort)(r >> 16);
}
__device__ __forceinline__ void split2(float x, ushort& hi, ushort& lo) {
    hi = f2bf_rne(x);
    float hf = __uint_as_float(((unsigned)hi) << 16);
    lo = f2bf_rne(x - hf);
}

// ---------------- utility kernels ----------------

__global__ void zero_int_kernel(int* __restrict__ p, int n) {
    int i = blockIdx.x * blockDim.x + threadIdx.x;
    if (i < n) p[i] = 0;
}

__global__ void hist_kernel(const int* __restrict__ dst, int* __restrict__ cnt, int E) {
    int e = blockIdx.x * blockDim.x + threadIdx.x;
    if (e < E) atomicAdd(&cnt[dst[e]], 1);
}

// exclusive scan over cnt -> row_ptr + cursor; single block, shuffle-based
__global__ __launch_bounds__(1024) void scan_kernel(const int* __restrict__ cnt,
                                                    int* __restrict__ row_ptr,
                                                    int* __restrict__ cursor, int N) {
    __shared__ int wsum[16];
    const int tid = threadIdx.x;
    const int lane = tid & 63;
    const int wv = tid >> 6;
    int running = 0;
    for (int base = 0; base < N; base += 1024) {
        const int i = base + tid;
        const int v = (i < N) ? cnt[i] : 0;
        int x = v;
#pragma unroll
        for (int off = 1; off < 64; off <<= 1) {
            int t = __shfl_up(x, off, 64);
            if (lane >= off) x += t;
        }
        if (lane == 63) wsum[wv] = x;
        __syncthreads();
        if (wv == 0) {
            int s = (lane < 16) ? wsum[lane] : 0;
#pragma unroll
            for (int off = 1; off < 16; off <<= 1) {
                int t = __shfl_up(s, off, 64);
                if (lane >= off) s += t;
            }
            if (lane < 16) wsum[lane] = s;
        }
        __syncthreads();
        const int woff = (wv > 0) ? wsum[wv - 1] : 0;
        const int total = wsum[15];
        if (i < N) {
            int ex = running + woff + x - v;
            row_ptr[i] = ex;
            cursor[i] = ex;
        }
        running += total;
        __syncthreads();
    }
    if (tid == 0) row_ptr[N] = running;
}

__global__ void scatter_kernel(const int* __restrict__ src, const int* __restrict__ dst,
                               int* __restrict__ cursor, int* __restrict__ csr, int E) {
    int e = blockIdx.x * blockDim.x + threadIdx.x;
    if (e < E) {
        int p = atomicAdd(&cursor[dst[e]], 1);
        csr[p] = src[e];
    }
}

// Fused: x split (float4 granular) + all weight transposes/splits.
__global__ void prep_all(const float* __restrict__ x, int nx4,
                         ushort* __restrict__ x_hi, ushort* __restrict__ x_lo,
                         const float* __restrict__ W1a, const float* __restrict__ W1b,
                         const float* __restrict__ W2a, const float* __restrict__ W2b,
                         ushort* __restrict__ T1a_h, ushort* __restrict__ T1a_l,
                         ushort* __restrict__ T1b_h,
                         ushort* __restrict__ T2a_h,
                         ushort* __restrict__ T2b_h, ushort* __restrict__ T2b_l) {
    int i = blockIdx.x * blockDim.x + threadIdx.x;
    if (i < nx4) {
        float4 v = ((const float4*)x)[i];
        ushort4 h, l;
        split2(v.x, h.x, l.x);
        split2(v.y, h.y, l.y);
        split2(v.z, h.z, l.z);
        split2(v.w, h.w, l.w);
        ((ushort4*)x_hi)[i] = h;
        ((ushort4*)x_lo)[i] = l;
        return;
    }
    int j = i - nx4;
    if (j < 65536) {  // T1a [n<512][k<128] hi/lo; src W1a [256][256]
        int n = j >> 7, k = j & 127;
        float v = (n < 256) ? W1a[k * 256 + n] : W1a[(128 + k) * 256 + (n - 256)];
        ushort h, l;
        split2(v, h, l);
        T1a_h[j] = h;
        T1a_l[j] = l;
    } else if (j < 131072) {  // T1b [n<256][k<256] hi only; src W1b [256][256]
        int t = j - 65536;
        int n = t >> 8, k = t & 255;
        T1b_h[t] = f2bf_rne(W1b[k * 256 + n]);
    } else if (j < 196608) {  // T2a [n<256][k<256] hi only; src W2a [512][128]
        int t = j - 131072;
        int n = t >> 8, k = t & 255;
        float v = (n < 128) ? W2a[k * 128 + n] : W2a[(256 + k) * 128 + (n - 128)];
        T2a_h[t] = f2bf_rne(v);
    } else if (j < 212992) {  // T2b [n<128][k<128] hi/lo; src W2b [128][128]
        int t = j - 196608;
        int n = t >> 7, k = t & 127;
        ushort h, l;
        split2(W2b[k * 128 + n], h, l);
        T2b_h[t] = h;
        T2b_l[t] = l;
    }
}

// ---------------- bf16 MFMA GEMM (1-pass or 3-pass compensated) ----------------
// A[M][K] bf16 (hi, + lo if THREE); B transposed [Nc][K] (hi, + lo if THREE).
// Tile BM=128,BN=64,BK=32; 4 waves. MODE 0: f32 out (+bias,+gate,+relu).
// MODE 1: dual — col<nsplit -> f32+bias (ld nsplit); col>=nsplit -> bf16.
// MODE 2: hi/lo out. MODE 3: bf16 out (+bias,+gate,+relu).

#define GBM 128
#define GBN 64
#define GBK 32
#define LDSW 40

template <int MODE, int THREE>
__global__ __launch_bounds__(256) void gemm_bf3(
    const ushort* __restrict__ Ahi, const ushort* __restrict__ Alo, int M, int K,
    const ushort* __restrict__ BThi, const ushort* __restrict__ BTlo,
    const float* __restrict__ bias, const int* __restrict__ gate, int relu,
    float* __restrict__ Cf, ushort* __restrict__ Chi, ushort* __restrict__ Clo,
    int Nc, int nsplit) {
    __shared__ ushort sAh[GBM * LDSW];
    __shared__ ushort sBh[GBN * LDSW];
    __shared__ ushort sAl[THREE ? GBM * LDSW : 1];
    __shared__ ushort sBl[THREE ? GBN * LDSW : 1];

    const int tid = threadIdx.x;
    const int lane = tid & 63;
    const int w = tid >> 6;
    const int wm = w >> 1, wn = w & 1;
    const int r16 = lane & 15, kg = lane >> 4;
    const int m0 = blockIdx.x * GBM;
    const int n0 = blockIdx.y * GBN;

    const int arow = tid >> 1, ahalf = tid & 1;   // A: 2 thr/row, 16 ushorts (2x int4)
    const int brow = tid >> 2, bchunk = tid & 3;  // B: 4 thr/row, 8 ushorts (1x int4)

    f32x4 acc[4][2];
#pragma unroll
    for (int i = 0; i < 4; i++)
#pragma unroll
        for (int j = 0; j < 2; j++) acc[i][j] = (f32x4)0.f;

    for (int kt = 0; kt < K; kt += GBK) {
        {
            const int gr = m0 + arow;
            const size_t go = (size_t)gr * K + kt + ahalf * 16;
            int4 h0 = make_int4(0, 0, 0, 0), h1 = h0;
            if (gr < M) {
                h0 = *(const int4*)(Ahi + go);
                h1 = *(const int4*)(Ahi + go + 8);
            }
            ushort* dh = sAh + arow * LDSW + ahalf * 16;
            *(int4*)(dh) = h0;
            *(int4*)(dh + 8) = h1;
            if constexpr (THREE) {
                int4 l0 = make_int4(0, 0, 0, 0), l1 = l0;
                if (gr < M) {
                    l0 = *(const int4*)(Alo + go);
                    l1 = *(const int4*)(Alo + go + 8);
                }
                ushort* dl = sAl + arow * LDSW + ahalf * 16;
                *(int4*)(dl) = l0;
                *(int4*)(dl + 8) = l1;
            }
        }
        {
            const size_t go = (size_t)(n0 + brow) * K + kt + bchunk * 8;
            *(int4*)(sBh + brow * LDSW + bchunk * 8) = *(const int4*)(BThi + go);
            if constexpr (THREE) {
                *(int4*)(sBl + brow * LDSW + bchunk * 8) = *(const int4*)(BTlo + go);
            }
        }
        __syncthreads();

        bf16x8 ah[4], bh[2];
#pragma unroll
        for (int mi = 0; mi < 4; mi++)
            ah[mi] = *(const bf16x8*)(sAh + (wm * 64 + mi * 16 + r16) * LDSW + kg * 8);
#pragma unroll
        for (int ni = 0; ni < 2; ni++)
            bh[ni] = *(const bf16x8*)(sBh + (wn * 32 + ni * 16 + r16) * LDSW + kg * 8);

        if constexpr (THREE) {
            bf16x8 al[4], bl[2];
#pragma unroll
            for (int mi = 0; mi < 4; mi++)
                al[mi] = *(const bf16x8*)(sAl + (wm * 64 + mi * 16 + r16) * LDSW + kg * 8);
#pragma unroll
            for (int ni = 0; ni < 2; ni++)
                bl[ni] = *(const bf16x8*)(sBl + (wn * 32 + ni * 16 + r16) * LDSW + kg * 8);
#pragma unroll
            for (int mi = 0; mi < 4; mi++)
#pragma unroll
                for (int ni = 0; ni < 2; ni++) {
                    acc[mi][ni] = __builtin_amdgcn_mfma_f32_16x16x32_bf16(ah[mi], bh[ni], acc[mi][ni], 0, 0, 0);
                    acc[mi][ni] = __builtin_amdgcn_mfma_f32_16x16x32_bf16(ah[mi], bl[ni], acc[mi][ni], 0, 0, 0);
                    acc[mi][ni] = __builtin_amdgcn_mfma_f32_16x16x32_bf16(al[mi], bh[ni], acc[mi][ni], 0, 0, 0);
                }
        } else {
#pragma unroll
            for (int mi = 0; mi < 4; mi++)
#pragma unroll
                for (int ni = 0; ni < 2; ni++)
                    acc[mi][ni] = __builtin_amdgcn_mfma_f32_16x16x32_bf16(ah[mi], bh[ni], acc[mi][ni], 0, 0, 0);
        }
        __syncthreads();
    }

    // epilogue: C/D mapping col=lane&15, row=(lane>>4)*4+reg  [m89-verified]
#pragma unroll
    for (int ni = 0; ni < 2; ni++) {
        const int col = n0 + wn * 32 + ni * 16 + r16;
        float bv = 0.f;
        if constexpr (MODE == 1) {
            bv = (col < nsplit && bias) ? bias[col] : 0.f;
        } else {
            bv = bias ? bias[col] : 0.f;
        }
#pragma unroll
        for (int mi = 0; mi < 4; mi++) {
#pragma unroll
            for (int r = 0; r < 4; r++) {
                const int row = m0 + wm * 64 + mi * 16 + kg * 4 + r;
                if (row >= M) continue;
                if constexpr (MODE == 1) {
                    const float v = acc[mi][ni][r];
                    if (col < nsplit) {
                        Cf[(size_t)row * nsplit + col] = v + bv;
                    } else {
                        Chi[(size_t)row * (Nc - nsplit) + (col - nsplit)] = f2bf_rne(v);
                    }
                } else {
                    float g = 1.f;
                    if (gate) g = (gate[row] > 0) ? 1.f : 0.f;
                    float v = acc[mi][ni][r] + bv * g;
                    if (relu) v = fmaxf(v, 0.f);
                    const size_t o = (size_t)row * Nc + col;
                    if constexpr (MODE == 0) {
                        Cf[o] = v;
                    } else if constexpr (MODE == 3) {
                        Chi[o] = f2bf_rne(v);
                    } else {
                        ushort h, l;
                        split2(v, h, l);
                        Chi[o] = h;
                        Clo[o] = l;
                    }
                }
            }
        }
    }
}

// ---------------- CSR mean aggregation, XCD-sliced ----------------
// Slice (64 feats) via blockIdx%8 -> per-XCD resident Pbot set 2.56MB < 4MB L2.
// fq=lane&15 (ushort4 feats), es=lane>>4 (edge group). Full 32-edge blocks run an
// UNPREDICATED body; exactly one predicated batch covers the tail (no serial loop).
// SPLIT: 1 -> write hi/lo bf16, 0 -> hi only.

template <int H, int SPLIT>
__global__ __launch_bounds__(256) void agg_x(const float* __restrict__ Ptop,
                                             const ushort* __restrict__ Pbot,
                                             const int* __restrict__ row_ptr,
                                             const int* __restrict__ csr,
                                             ushort* __restrict__ Shi,
                                             ushort* __restrict__ Slo, int N) {
    constexpr int SLICES = H / 64;
    constexpr int XPS = 8 / SLICES;  // XCDs per slice

    const int bid = blockIdx.x;
    const int xcd = bid & 7;
    const int grp = bid >> 3;
    const int slice = xcd / XPS;
    const int subx = xcd % XPS;
    const int wave = threadIdx.x >> 6;
    const int lane = threadIdx.x & 63;

    const int n = (grp * XPS + subx) * 4 + wave;
    if (n >= N) return;
    const int qoff = slice * 64;

    const int fq = lane & 15;  // feature quad (4 feats, 8B)
    const int es = lane >> 4;  // edge group 0..3

    const int begin = row_ptr[n];
    const int end = row_ptr[n + 1];
    const int deg = end - begin;

    const float4 top = *(const float4*)(Ptop + (size_t)n * H + qoff + fq * 4);
    float a0 = 0.f, a1 = 0.f, a2 = 0.f, a3 = 0.f;

    int e = begin;
    const int nfull = deg >> 5;
    for (int b = 0; b < nfull; b++, e += 32) {
        int idx[8];
#pragma unroll
        for (int j = 0; j < 8; j++) idx[j] = csr[e + j * 4 + es];
        ushort4 v[8];
#pragma unroll
        for (int j = 0; j < 8; j++)
            v[j] = *(const ushort4*)(Pbot + (size_t)idx[j] * H + qoff + fq * 4);
#pragma unroll
        for (int j = 0; j < 8; j++) {
            a0 += fmaxf(top.x + bf2f(v[j].x), 0.f);
            a1 += fmaxf(top.y + bf2f(v[j].y), 0.f);
            a2 += fmaxf(top.z + bf2f(v[j].z), 0.f);
            a3 += fmaxf(top.w + bf2f(v[j].w), 0.f);
        }
    }
    if (e < end) {  // one predicated batch for the tail (<32 edges)
        int idx[8];
        float m[8];
#pragma unroll
        for (int j = 0; j < 8; j++) {
            const int t = e + j * 4 + es;
            const bool valid = t < end;
            idx[j] = csr[valid ? t : begin];
            m[j] = valid ? 1.f : 0.f;
        }
        ushort4 v[8];
#pragma unroll
        for (int j = 0; j < 8; j++)
            v[j] = *(const ushort4*)(Pbot + (size_t)idx[j] * H + qoff + fq * 4);
#pragma unroll
        for (int j = 0; j < 8; j++) {
            a0 = fmaf(m[j], fmaxf(top.x + bf2f(v[j].x), 0.f), a0);
            a1 = fmaf(m[j], fmaxf(top.y + bf2f(v[j].y), 0.f), a1);
            a2 = fmaf(m[j], fmaxf(top.z + bf2f(v[j].z), 0.f), a2);
            a3 = fmaf(m[j], fmaxf(top.w + bf2f(v[j].w), 0.f), a3);
        }
    }

    // combine the 4 edge groups (lanes differing in bits 4,5)
    a0 += __shfl_xor(a0, 16, 64);
    a1 += __shfl_xor(a1, 16, 64);
    a2 += __shfl_xor(a2, 16, 64);
    a3 += __shfl_xor(a3, 16, 64);
    a0 += __shfl_xor(a0, 32, 64);
    a1 += __shfl_xor(a1, 32, 64);
    a2 += __shfl_xor(a2, 32, 64);
    a3 += __shfl_xor(a3, 32, 64);

    if (es == 0) {
        const float inv = (deg > 0) ? 1.f / (float)deg : 0.f;
        if constexpr (SPLIT) {
            ushort4 h, l;
            split2(a0 * inv, h.x, l.x);
            split2(a1 * inv, h.y, l.y);
            split2(a2 * inv, h.z, l.z);
            split2(a3 * inv, h.w, l.w);
            *(ushort4*)(Shi + (size_t)n * H + qoff + fq * 4) = h;
            *(ushort4*)(Slo + (size_t)n * H + qoff + fq * 4) = l;
        } else {
            ushort4 h;
            h.x = f2bf_rne(a0 * inv);
            h.y = f2bf_rne(a1 * inv);
            h.z = f2bf_rne(a2 * inv);
            h.w = f2bf_rne(a3 * inv);
            *(ushort4*)(Shi + (size_t)n * H + qoff + fq * 4) = h;
        }
    }
}

// ---------------- launch ----------------

extern "C" void kernel_launch(void* const* d_in, const int* in_sizes, int n_in,
                              void* d_out, int out_size, void* d_ws, size_t ws_size,
                              hipStream_t stream) {
    const int N = in_sizes[0] / NODE_DIM;  // 20000
    const int E = in_sizes[1] / 2;         // 640000

    const float* x = (const float*)d_in[0];
    const int* ei = (const int*)d_in[1];
    const int* e_src = ei;
    const int* e_dst = ei + E;
    const float* W1a = (const float*)d_in[2];
    const float* b1a = (const float*)d_in[3];
    const float* W1b = (const float*)d_in[4];
    const float* b1b = (const float*)d_in[5];
    const float* W2a = (const float*)d_in[6];
    const float* b2a = (const float*)d_in[7];
    const float* W2b = (const float*)d_in[8];
    const float* b2b = (const float*)d_in[9];

    char* ws = (char*)d_ws;
    size_t off = 0;
    auto alloc = [&](size_t bytes) {
        size_t o = off;
        off += (bytes + 255) & ~(size_t)255;
        return o;
    };
    int* cnt = (int*)(ws + alloc((size_t)N * 4));
    int* row_ptr = (int*)(ws + alloc((size_t)(N + 1) * 4));
    int* cursor = (int*)(ws + alloc((size_t)N * 4));
    int* csr = (int*)(ws + alloc((size_t)E * 4));
    ushort* x_hi = (ushort*)(ws + alloc((size_t)N * NODE_DIM * 2));
    ushort* x_lo = (ushort*)(ws + alloc((size_t)N * NODE_DIM * 2));
    ushort* T1a_h = (ushort*)(ws + alloc((size_t)(2 * HID) * NODE_DIM * 2));  // [512][128]
    ushort* T1a_l = (ushort*)(ws + alloc((size_t)(2 * HID) * NODE_DIM * 2));
    ushort* T1b_h = (ushort*)(ws + alloc((size_t)HID * HID * 2));
    ushort* T2a_h = (ushort*)(ws + alloc((size_t)(2 * OUTD) * HID * 2));  // [256][256]
    ushort* T2b_h = (ushort*)(ws + alloc((size_t)OUTD * OUTD * 2));
    ushort* T2b_l = (ushort*)(ws + alloc((size_t)OUTD * OUTD * 2));
    float* P1t = (float*)(ws + alloc((size_t)N * HID * 4));
    ushort* P1b = (ushort*)(ws + alloc((size_t)N * HID * 2));
    ushort* S1h = (ushort*)(ws + alloc((size_t)N * HID * 2));
    ushort* S2l = (ushort*)(ws + alloc((size_t)N * HID * 2));
    ushort* h_hi = (ushort*)(ws + alloc((size_t)N * HID * 2));
    float* P2t = P1t;
    ushort* P2b = P1b;
    ushort* S2h = S1h;

    // CSR build
    zero_int_kernel<<<(N + 255) / 256, 256, 0, stream>>>(cnt, N);
    hist_kernel<<<(E + 255) / 256, 256, 0, stream>>>(e_dst, cnt, E);
    scan_kernel<<<1, 1024, 0, stream>>>(cnt, row_ptr, cursor, N);
    scatter_kernel<<<(E + 255) / 256, 256, 0, stream>>>(e_src, e_dst, cursor, csr, E);

    // fused input/weight prep
    const int nx4 = N * NODE_DIM / 4;
    prep_all<<<(nx4 + 212992 + 255) / 256, 256, 0, stream>>>(
        x, nx4, x_hi, x_lo, W1a, W1b, W2a, W2b,
        T1a_h, T1a_l, T1b_h, T2a_h, T2b_h, T2b_l);

    const int MT = (N + GBM - 1) / GBM;  // 157
    const int AB1 = 8 * ((N + 4 * 2 - 1) / (4 * 2));  // H=256: XPS=2
    const int AB2 = 8 * ((N + 4 * 4 - 1) / (4 * 4));  // H=128: XPS=4

    // Layer 1: merged projection, 3-pass (x is the largest error source)
    gemm_bf3<1, 1><<<dim3(MT, (2 * HID) / GBN), 256, 0, stream>>>(
        x_hi, x_lo, N, NODE_DIM, T1a_h, T1a_l, b1a, nullptr, 0,
        P1t, P1b, nullptr, 2 * HID, HID);
    agg_x<HID, 0><<<AB1, 256, 0, stream>>>(P1t, P1b, row_ptr, csr, S1h, nullptr, N);
    // S1@W1b: 1-pass bf16 -> h (bf16, bias gated, relu)
    gemm_bf3<3, 0><<<dim3(MT, HID / GBN), 256, 0, stream>>>(
        S1h, nullptr, N, HID, T1b_h, nullptr, b1b, cnt, 1,
        nullptr, h_hi, nullptr, HID, 0);

    // Layer 2: merged projection, 1-pass
    gemm_bf3<1, 0><<<dim3(MT, (2 * OUTD) / GBN), 256, 0, stream>>>(
        h_hi, nullptr, N, HID, T2a_h, nullptr, b2a, nullptr, 0,
        P2t, P2b, nullptr, 2 * OUTD, OUTD);
    agg_x<OUTD, 1><<<AB2, 256, 0, stream>>>(P2t, P2b, row_ptr, csr, S2h, S2l, N);
    // final GEMM: 3-pass (direct to output)
    gemm_bf3<0, 1><<<dim3(MT, OUTD / GBN), 256, 0, stream>>>(
        S2h, S2l, N, OUTD, T2b_h, T2b_l, b2b, cnt, 0,
        (float*)d_out, nullptr, nullptr, OUTD, 0);
}

// Round 10
// 244.832 us; speedup vs baseline: 1.2115x; 1.0194x over previous
//
#include <hip/hip_runtime.h>
#include <hip/hip_bf16.h>

// GraphEncoder: 2-layer GNN, edge-MLP + scatter-mean.
//   cat(x_dst,x_src)@Wa = (x@Wa_top)[dst] + (x@Wa_bot)[src]
//   mean_agg(relu(pre)@Wb + bb) = mean_agg(relu(pre))@Wb + (cnt>0)*bb
// R10: padded CSR — each node's edge list padded to 32-multiple with index N;
//      Pbot row N = bf16 -inf so relu(top + -inf) = 0. Agg body is fully
//      unpredicated (R9: tail predication was ~half the VALU issue). Separate
//      (N+1)-row P2b so both layers have a poison row. 10 dispatches.

#define NODE_DIM 128
#define HID 256
#define OUTD 128

typedef __attribute__((ext_vector_type(8))) short bf16x8;
typedef __attribute__((ext_vector_type(4))) float f32x4;

__device__ __forceinline__ float bf2f(ushort u) {
    return __uint_as_float(((unsigned)u) << 16);
}
__device__ __forceinline__ ushort f2bf_rne(float x) {
    unsigned u = __float_as_uint(x);
    unsigned r = u + 0x7fffu + ((u >> 16) & 1u);
    return (ushort)(r >> 16);
}
__device__ __forceinline__ void split2(float x, ushort& hi, ushort& lo) {
    hi = f2bf_rne(x);
    float hf = __uint_as_float(((unsigned)hi) << 16);
    lo = f2bf_rne(x - hf);
}

// ---------------- CSR build ----------------

// hist + pre-fill padded csr with poison index N
__global__ void hist_fill_kernel(const int* __restrict__ dst, int* __restrict__ cnt,
                                 int E, int* __restrict__ csr, int Epad, int N) {
    int i = blockIdx.x * blockDim.x + threadIdx.x;
    if (i < Epad) csr[i] = N;
    if (i < E) atomicAdd(&cnt[dst[i]], 1);
}

// exclusive scan of PADDED counts (ceil(cnt/32)*32) -> row_ptr + cursor
__global__ __launch_bounds__(1024) void scan_kernel(const int* __restrict__ cnt,
                                                    int* __restrict__ row_ptr,
                                                    int* __restrict__ cursor, int N) {
    __shared__ int wsum[16];
    const int tid = threadIdx.x;
    const int lane = tid & 63;
    const int wv = tid >> 6;
    int running = 0;
    for (int base = 0; base < N; base += 1024) {
        const int i = base + tid;
        const int v = (i < N) ? ((cnt[i] + 31) & ~31) : 0;
        int x = v;
#pragma unroll
        for (int off = 1; off < 64; off <<= 1) {
            int t = __shfl_up(x, off, 64);
            if (lane >= off) x += t;
        }
        if (lane == 63) wsum[wv] = x;
        __syncthreads();
        if (wv == 0) {
            int s = (lane < 16) ? wsum[lane] : 0;
#pragma unroll
            for (int off = 1; off < 16; off <<= 1) {
                int t = __shfl_up(s, off, 64);
                if (lane >= off) s += t;
            }
            if (lane < 16) wsum[lane] = s;
        }
        __syncthreads();
        const int woff = (wv > 0) ? wsum[wv - 1] : 0;
        const int total = wsum[15];
        if (i < N) {
            int ex = running + woff + x - v;
            row_ptr[i] = ex;
            cursor[i] = ex;
        }
        running += total;
        __syncthreads();
    }
    if (tid == 0) row_ptr[N] = running;
}

__global__ void scatter_kernel(const int* __restrict__ src, const int* __restrict__ dst,
                               int* __restrict__ cursor, int* __restrict__ csr, int E) {
    int e = blockIdx.x * blockDim.x + threadIdx.x;
    if (e < E) {
        int p = atomicAdd(&cursor[dst[e]], 1);
        csr[p] = src[e];
    }
}

// Fused: x split + weight transposes/splits + cnt zero + Pbot poison rows.
__global__ void prep_all(const float* __restrict__ x, int nx4,
                         ushort* __restrict__ x_hi, ushort* __restrict__ x_lo,
                         const float* __restrict__ W1a, const float* __restrict__ W1b,
                         const float* __restrict__ W2a, const float* __restrict__ W2b,
                         ushort* __restrict__ T1a_h, ushort* __restrict__ T1a_l,
                         ushort* __restrict__ T1b_h,
                         ushort* __restrict__ T2a_h,
                         ushort* __restrict__ T2b_h, ushort* __restrict__ T2b_l,
                         int* __restrict__ cnt, int N,
                         ushort* __restrict__ P1b, ushort* __restrict__ P2b) {
    int i = blockIdx.x * blockDim.x + threadIdx.x;
    if (i < nx4) {
        float4 v = ((const float4*)x)[i];
        ushort4 h, l;
        split2(v.x, h.x, l.x);
        split2(v.y, h.y, l.y);
        split2(v.z, h.z, l.z);
        split2(v.w, h.w, l.w);
        ((ushort4*)x_hi)[i] = h;
        ((ushort4*)x_lo)[i] = l;
        return;
    }
    int j = i - nx4;
    if (j < 65536) {  // T1a [n<512][k<128] hi/lo; src W1a [256][256]
        int n = j >> 7, k = j & 127;
        float v = (n < 256) ? W1a[k * 256 + n] : W1a[(128 + k) * 256 + (n - 256)];
        ushort h, l;
        split2(v, h, l);
        T1a_h[j] = h;
        T1a_l[j] = l;
        return;
    }
    if (j < 131072) {  // T1b [n<256][k<256] hi only; src W1b [256][256]
        int t = j - 65536;
        int n = t >> 8, k = t & 255;
        T1b_h[t] = f2bf_rne(W1b[k * 256 + n]);
        return;
    }
    if (j < 196608) {  // T2a [n<256][k<256] hi only; src W2a [512][128]
        int t = j - 131072;
        int n = t >> 8, k = t & 255;
        float v = (n < 128) ? W2a[k * 128 + n] : W2a[(256 + k) * 128 + (n - 128)];
        T2a_h[t] = f2bf_rne(v);
        return;
    }
    if (j < 212992) {  // T2b [n<128][k<128] hi/lo; src W2b [128][128]
        int t = j - 196608;
        int n = t >> 7, k = t & 127;
        ushort h, l;
        split2(W2b[k * 128 + n], h, l);
        T2b_h[t] = h;
        T2b_l[t] = l;
        return;
    }
    int k = j - 212992;
    if (k < N) {  // zero cnt
        cnt[k] = 0;
        return;
    }
    k -= N;
    if (k < HID) {  // P1b poison row (index N): bf16 -inf
        P1b[(size_t)N * HID + k] = 0xFF80;
        return;
    }
    k -= HID;
    if (k < OUTD) {  // P2b poison row
        P2b[(size_t)N * OUTD + k] = 0xFF80;
    }
}

// ---------------- bf16 MFMA GEMM (1-pass or 3-pass compensated) ----------------
// A[M][K] bf16 (hi, + lo if THREE); B transposed [Nc][K] (hi, + lo if THREE).
// Tile BM=128,BN=64,BK=32; 4 waves. MODE 0: f32 out (+bias,+gate,+relu).
// MODE 1: dual — col<nsplit -> f32+bias (ld nsplit); col>=nsplit -> bf16.
// MODE 2: hi/lo out. MODE 3: bf16 out (+bias,+gate,+relu).

#define GBM 128
#define GBN 64
#define GBK 32
#define LDSW 40

template <int MODE, int THREE>
__global__ __launch_bounds__(256) void gemm_bf3(
    const ushort* __restrict__ Ahi, const ushort* __restrict__ Alo, int M, int K,
    const ushort* __restrict__ BThi, const ushort* __restrict__ BTlo,
    const float* __restrict__ bias, const int* __restrict__ gate, int relu,
    float* __restrict__ Cf, ushort* __restrict__ Chi, ushort* __restrict__ Clo,
    int Nc, int nsplit) {
    __shared__ ushort sAh[GBM * LDSW];
    __shared__ ushort sBh[GBN * LDSW];
    __shared__ ushort sAl[THREE ? GBM * LDSW : 1];
    __shared__ ushort sBl[THREE ? GBN * LDSW : 1];

    const int tid = threadIdx.x;
    const int lane = tid & 63;
    const int w = tid >> 6;
    const int wm = w >> 1, wn = w & 1;
    const int r16 = lane & 15, kg = lane >> 4;
    const int m0 = blockIdx.x * GBM;
    const int n0 = blockIdx.y * GBN;

    const int arow = tid >> 1, ahalf = tid & 1;   // A: 2 thr/row, 16 ushorts (2x int4)
    const int brow = tid >> 2, bchunk = tid & 3;  // B: 4 thr/row, 8 ushorts (1x int4)

    f32x4 acc[4][2];
#pragma unroll
    for (int i = 0; i < 4; i++)
#pragma unroll
        for (int j = 0; j < 2; j++) acc[i][j] = (f32x4)0.f;

    for (int kt = 0; kt < K; kt += GBK) {
        {
            const int gr = m0 + arow;
            const size_t go = (size_t)gr * K + kt + ahalf * 16;
            int4 h0 = make_int4(0, 0, 0, 0), h1 = h0;
            if (gr < M) {
                h0 = *(const int4*)(Ahi + go);
                h1 = *(const int4*)(Ahi + go + 8);
            }
            ushort* dh = sAh + arow * LDSW + ahalf * 16;
            *(int4*)(dh) = h0;
            *(int4*)(dh + 8) = h1;
            if constexpr (THREE) {
                int4 l0 = make_int4(0, 0, 0, 0), l1 = l0;
                if (gr < M) {
                    l0 = *(const int4*)(Alo + go);
                    l1 = *(const int4*)(Alo + go + 8);
                }
                ushort* dl = sAl + arow * LDSW + ahalf * 16;
                *(int4*)(dl) = l0;
                *(int4*)(dl + 8) = l1;
            }
        }
        {
            const size_t go = (size_t)(n0 + brow) * K + kt + bchunk * 8;
            *(int4*)(sBh + brow * LDSW + bchunk * 8) = *(const int4*)(BThi + go);
            if constexpr (THREE) {
                *(int4*)(sBl + brow * LDSW + bchunk * 8) = *(const int4*)(BTlo + go);
            }
        }
        __syncthreads();

        bf16x8 ah[4], bh[2];
#pragma unroll
        for (int mi = 0; mi < 4; mi++)
            ah[mi] = *(const bf16x8*)(sAh + (wm * 64 + mi * 16 + r16) * LDSW + kg * 8);
#pragma unroll
        for (int ni = 0; ni < 2; ni++)
            bh[ni] = *(const bf16x8*)(sBh + (wn * 32 + ni * 16 + r16) * LDSW + kg * 8);

        if constexpr (THREE) {
            bf16x8 al[4], bl[2];
#pragma unroll
            for (int mi = 0; mi < 4; mi++)
                al[mi] = *(const bf16x8*)(sAl + (wm * 64 + mi * 16 + r16) * LDSW + kg * 8);
#pragma unroll
            for (int ni = 0; ni < 2; ni++)
                bl[ni] = *(const bf16x8*)(sBl + (wn * 32 + ni * 16 + r16) * LDSW + kg * 8);
#pragma unroll
            for (int mi = 0; mi < 4; mi++)
#pragma unroll
                for (int ni = 0; ni < 2; ni++) {
                    acc[mi][ni] = __builtin_amdgcn_mfma_f32_16x16x32_bf16(ah[mi], bh[ni], acc[mi][ni], 0, 0, 0);
                    acc[mi][ni] = __builtin_amdgcn_mfma_f32_16x16x32_bf16(ah[mi], bl[ni], acc[mi][ni], 0, 0, 0);
                    acc[mi][ni] = __builtin_amdgcn_mfma_f32_16x16x32_bf16(al[mi], bh[ni], acc[mi][ni], 0, 0, 0);
                }
        } else {
#pragma unroll
            for (int mi = 0; mi < 4; mi++)
#pragma unroll
                for (int ni = 0; ni < 2; ni++)
                    acc[mi][ni] = __builtin_amdgcn_mfma_f32_16x16x32_bf16(ah[mi], bh[ni], acc[mi][ni], 0, 0, 0);
        }
        __syncthreads();
    }

    // epilogue: C/D mapping col=lane&15, row=(lane>>4)*4+reg  [m89-verified]
#pragma unroll
    for (int ni = 0; ni < 2; ni++) {
        const int col = n0 + wn * 32 + ni * 16 + r16;
        float bv = 0.f;
        if constexpr (MODE == 1) {
            bv = (col < nsplit && bias) ? bias[col] : 0.f;
        } else {
            bv = bias ? bias[col] : 0.f;
        }
#pragma unroll
        for (int mi = 0; mi < 4; mi++) {
#pragma unroll
            for (int r = 0; r < 4; r++) {
                const int row = m0 + wm * 64 + mi * 16 + kg * 4 + r;
                if (row >= M) continue;
                if constexpr (MODE == 1) {
                    const float v = acc[mi][ni][r];
                    if (col < nsplit) {
                        Cf[(size_t)row * nsplit + col] = v + bv;
                    } else {
                        Chi[(size_t)row * (Nc - nsplit) + (col - nsplit)] = f2bf_rne(v);
                    }
                } else {
                    float g = 1.f;
                    if (gate) g = (gate[row] > 0) ? 1.f : 0.f;
                    float v = acc[mi][ni][r] + bv * g;
                    if (relu) v = fmaxf(v, 0.f);
                    const size_t o = (size_t)row * Nc + col;
                    if constexpr (MODE == 0) {
                        Cf[o] = v;
                    } else if constexpr (MODE == 3) {
                        Chi[o] = f2bf_rne(v);
                    } else {
                        ushort h, l;
                        split2(v, h, l);
                        Chi[o] = h;
                        Clo[o] = l;
                    }
                }
            }
        }
    }
}

// ---------------- CSR mean aggregation, XCD-sliced, padded (no predication) ----------
// row_ptr holds 32-ALIGNED padded offsets; pad slots index the poison row N whose
// bf16 value is -inf -> relu contributes exact 0. deg comes from cnt[].
// Slice (64 feats) via blockIdx%8 -> per-XCD resident Pbot set < 4MB L2.
// fq=lane&15 (ushort4 feats), es=lane>>4 (edge group). SPLIT: 1 -> hi/lo out.

template <int H, int SPLIT>
__global__ __launch_bounds__(256) void agg_x(const float* __restrict__ Ptop,
                                             const ushort* __restrict__ Pbot,
                                             const int* __restrict__ row_ptr,
                                             const int* __restrict__ cnt,
                                             const int* __restrict__ csr,
                                             ushort* __restrict__ Shi,
                                             ushort* __restrict__ Slo, int N) {
    constexpr int SLICES = H / 64;
    constexpr int XPS = 8 / SLICES;  // XCDs per slice

    const int bid = blockIdx.x;
    const int xcd = bid & 7;
    const int grp = bid >> 3;
    const int slice = xcd / XPS;
    const int subx = xcd % XPS;
    const int wave = threadIdx.x >> 6;
    const int lane = threadIdx.x & 63;

    const int n = (grp * XPS + subx) * 4 + wave;
    if (n >= N) return;
    const int qoff = slice * 64;

    const int fq = lane & 15;  // feature quad (4 feats, 8B)
    const int es = lane >> 4;  // edge group 0..3

    const int begin = row_ptr[n];
    const int end = row_ptr[n + 1];  // padded, multiple of 32
    const int deg = cnt[n];

    const float4 top = *(const float4*)(Ptop + (size_t)n * H + qoff + fq * 4);
    float a0 = 0.f, a1 = 0.f, a2 = 0.f, a3 = 0.f;

    for (int e = begin; e < end; e += 32) {
        int idx[8];
#pragma unroll
        for (int j = 0; j < 8; j++) idx[j] = csr[e + j * 4 + es];
        ushort4 v[8];
#pragma unroll
        for (int j = 0; j < 8; j++)
            v[j] = *(const ushort4*)(Pbot + (size_t)idx[j] * H + qoff + fq * 4);
#pragma unroll
        for (int j = 0; j < 8; j++) {
            a0 += fmaxf(top.x + bf2f(v[j].x), 0.f);
            a1 += fmaxf(top.y + bf2f(v[j].y), 0.f);
            a2 += fmaxf(top.z + bf2f(v[j].z), 0.f);
            a3 += fmaxf(top.w + bf2f(v[j].w), 0.f);
        }
    }

    // combine the 4 edge groups (lanes differing in bits 4,5)
    a0 += __shfl_xor(a0, 16, 64);
    a1 += __shfl_xor(a1, 16, 64);
    a2 += __shfl_xor(a2, 16, 64);
    a3 += __shfl_xor(a3, 16, 64);
    a0 += __shfl_xor(a0, 32, 64);
    a1 += __shfl_xor(a1, 32, 64);
    a2 += __shfl_xor(a2, 32, 64);
    a3 += __shfl_xor(a3, 32, 64);

    if (es == 0) {
        const float inv = (deg > 0) ? 1.f / (float)deg : 0.f;
        if constexpr (SPLIT) {
            ushort4 h, l;
            split2(a0 * inv, h.x, l.x);
            split2(a1 * inv, h.y, l.y);
            split2(a2 * inv, h.z, l.z);
            split2(a3 * inv, h.w, l.w);
            *(ushort4*)(Shi + (size_t)n * H + qoff + fq * 4) = h;
            *(ushort4*)(Slo + (size_t)n * H + qoff + fq * 4) = l;
        } else {
            ushort4 h;
            h.x = f2bf_rne(a0 * inv);
            h.y = f2bf_rne(a1 * inv);
            h.z = f2bf_rne(a2 * inv);
            h.w = f2bf_rne(a3 * inv);
            *(ushort4*)(Shi + (size_t)n * H + qoff + fq * 4) = h;
        }
    }
}

// ---------------- launch ----------------

extern "C" void kernel_launch(void* const* d_in, const int* in_sizes, int n_in,
                              void* d_out, int out_size, void* d_ws, size_t ws_size,
                              hipStream_t stream) {
    const int N = in_sizes[0] / NODE_DIM;  // 20000
    const int E = in_sizes[1] / 2;         // 640000
    const int Epad = E + 32 * N;           // padded csr capacity

    const float* x = (const float*)d_in[0];
    const int* ei = (const int*)d_in[1];
    const int* e_src = ei;
    const int* e_dst = ei + E;
    const float* W1a = (const float*)d_in[2];
    const float* b1a = (const float*)d_in[3];
    const float* W1b = (const float*)d_in[4];
    const float* b1b = (const float*)d_in[5];
    const float* W2a = (const float*)d_in[6];
    const float* b2a = (const float*)d_in[7];
    const float* W2b = (const float*)d_in[8];
    const float* b2b = (const float*)d_in[9];

    char* ws = (char*)d_ws;
    size_t off = 0;
    auto alloc = [&](size_t bytes) {
        size_t o = off;
        off += (bytes + 255) & ~(size_t)255;
        return o;
    };
    int* cnt = (int*)(ws + alloc((size_t)N * 4));
    int* row_ptr = (int*)(ws + alloc((size_t)(N + 1) * 4));
    int* cursor = (int*)(ws + alloc((size_t)N * 4));
    int* csr = (int*)(ws + alloc((size_t)Epad * 4));
    ushort* x_hi = (ushort*)(ws + alloc((size_t)N * NODE_DIM * 2));
    ushort* x_lo = (ushort*)(ws + alloc((size_t)N * NODE_DIM * 2));
    ushort* T1a_h = (ushort*)(ws + alloc((size_t)(2 * HID) * NODE_DIM * 2));  // [512][128]
    ushort* T1a_l = (ushort*)(ws + alloc((size_t)(2 * HID) * NODE_DIM * 2));
    ushort* T1b_h = (ushort*)(ws + alloc((size_t)HID * HID * 2));
    ushort* T2a_h = (ushort*)(ws + alloc((size_t)(2 * OUTD) * HID * 2));  // [256][256]
    ushort* T2b_h = (ushort*)(ws + alloc((size_t)OUTD * OUTD * 2));
    ushort* T2b_l = (ushort*)(ws + alloc((size_t)OUTD * OUTD * 2));
    float* P1t = (float*)(ws + alloc((size_t)N * HID * 4));
    ushort* P1b = (ushort*)(ws + alloc((size_t)(N + 1) * HID * 2));   // +poison row
    ushort* P2b = (ushort*)(ws + alloc((size_t)(N + 1) * OUTD * 2));  // +poison row
    ushort* S1h = (ushort*)(ws + alloc((size_t)N * HID * 2));
    ushort* S2l = (ushort*)(ws + alloc((size_t)N * OUTD * 2));
    ushort* h_hi = (ushort*)(ws + alloc((size_t)N * HID * 2));
    float* P2t = P1t;
    ushort* S2h = S1h;

    // prep (includes cnt zero + poison rows) -> CSR build
    const int nx4 = N * NODE_DIM / 4;
    const int prep_n = nx4 + 212992 + N + HID + OUTD;
    prep_all<<<(prep_n + 255) / 256, 256, 0, stream>>>(
        x, nx4, x_hi, x_lo, W1a, W1b, W2a, W2b,
        T1a_h, T1a_l, T1b_h, T2a_h, T2b_h, T2b_l, cnt, N, P1b, P2b);
    hist_fill_kernel<<<(Epad + 255) / 256, 256, 0, stream>>>(e_dst, cnt, E, csr, Epad, N);
    scan_kernel<<<1, 1024, 0, stream>>>(cnt, row_ptr, cursor, N);
    scatter_kernel<<<(E + 255) / 256, 256, 0, stream>>>(e_src, e_dst, cursor, csr, E);

    const int MT = (N + GBM - 1) / GBM;  // 157
    const int AB1 = 8 * ((N + 4 * 2 - 1) / (4 * 2));  // H=256: XPS=2
    const int AB2 = 8 * ((N + 4 * 4 - 1) / (4 * 4));  // H=128: XPS=4

    // Layer 1: merged projection, 3-pass (x is the largest error source)
    gemm_bf3<1, 1><<<dim3(MT, (2 * HID) / GBN), 256, 0, stream>>>(
        x_hi, x_lo, N, NODE_DIM, T1a_h, T1a_l, b1a, nullptr, 0,
        P1t, P1b, nullptr, 2 * HID, HID);
    agg_x<HID, 0><<<AB1, 256, 0, stream>>>(P1t, P1b, row_ptr, cnt, csr, S1h, nullptr, N);
    // S1@W1b: 1-pass bf16 -> h (bf16, bias gated, relu)
    gemm_bf3<3, 0><<<dim3(MT, HID / GBN), 256, 0, stream>>>(
        S1h, nullptr, N, HID, T1b_h, nullptr, b1b, cnt, 1,
        nullptr, h_hi, nullptr, HID, 0);

    // Layer 2: merged projection, 1-pass
    gemm_bf3<1, 0><<<dim3(MT, (2 * OUTD) / GBN), 256, 0, stream>>>(
        h_hi, nullptr, N, HID, T2a_h, nullptr, b2a, nullptr, 0,
        P2t, P2b, nullptr, 2 * OUTD, OUTD);
    agg_x<OUTD, 1><<<AB2, 256, 0, stream>>>(P2t, P2b, row_ptr, cnt, csr, S2h, S2l, N);
    // final GEMM: 3-pass (direct to output)
    gemm_bf3<0, 1><<<dim3(MT, OUTD / GBN), 256, 0, stream>>>(
        S2h, S2l, N, OUTD, T2b_h, T2b_l, b2b, cnt, 0,
        (float*)d_out, nullptr, nullptr, OUTD, 0);
}

// Round 12
// 232.286 us; speedup vs baseline: 1.2769x; 1.0540x over previous
//
#include <hip/hip_runtime.h>
#include <hip/hip_bf16.h>

// GraphEncoder: 2-layer GNN, edge-MLP + scatter-mean.
//   cat(x_dst,x_src)@Wa = (x@Wa_top)[dst] + (x@Wa_bot)[src]
//   mean_agg(relu(pre)@Wb + bb) = mean_agg(relu(pre))@Wb + (cnt>0)*bb
// R12 (=R11 fixed): agg full-row waves — wave = one node's full feature row
//      (lane=feature), edge loop WAVE-UNIFORM (csr scalar loads, SALU addressing,
//      no padding, no predication, no shuffles); P-gather payload fp16, math in
//      packed _Float16x2 (v_pk_add/max_f16) with f32 flush per 8-edge group.
//      Uses clang-native _Float16 vectors (ROCm __hadd2/__hmax2 overloads are
//      ambiguous between fp16/bf16 headers — R11 compile failure).

#define NODE_DIM 128
#define HID 256
#define OUTD 128

typedef __attribute__((ext_vector_type(8))) short bf16x8;
typedef __attribute__((ext_vector_type(4))) float f32x4;
typedef __attribute__((ext_vector_type(2))) _Float16 h2;

__device__ __forceinline__ float bf2f(ushort u) {
    return __uint_as_float(((unsigned)u) << 16);
}
__device__ __forceinline__ ushort f2bf_rne(float x) {
    unsigned u = __float_as_uint(x);
    unsigned r = u + 0x7fffu + ((u >> 16) & 1u);
    return (ushort)(r >> 16);
}
__device__ __forceinline__ void split2(float x, ushort& hi, ushort& lo) {
    hi = f2bf_rne(x);
    float hf = __uint_as_float(((unsigned)hi) << 16);
    lo = f2bf_rne(x - hf);
}
__device__ __forceinline__ h2 bc2(unsigned u) {
    return __builtin_bit_cast(h2, u);
}

// ---------------- CSR build ----------------

__global__ void hist_kernel(const int* __restrict__ dst, int* __restrict__ cnt, int E) {
    int e = blockIdx.x * blockDim.x + threadIdx.x;
    if (e < E) atomicAdd(&cnt[dst[e]], 1);
}

// exclusive scan over cnt -> row_ptr + cursor; single block, shuffle-based
__global__ __launch_bounds__(1024) void scan_kernel(const int* __restrict__ cnt,
                                                    int* __restrict__ row_ptr,
                                                    int* __restrict__ cursor, int N) {
    __shared__ int wsum[16];
    const int tid = threadIdx.x;
    const int lane = tid & 63;
    const int wv = tid >> 6;
    int running = 0;
    for (int base = 0; base < N; base += 1024) {
        const int i = base + tid;
        const int v = (i < N) ? cnt[i] : 0;
        int x = v;
#pragma unroll
        for (int off = 1; off < 64; off <<= 1) {
            int t = __shfl_up(x, off, 64);
            if (lane >= off) x += t;
        }
        if (lane == 63) wsum[wv] = x;
        __syncthreads();
        if (wv == 0) {
            int s = (lane < 16) ? wsum[lane] : 0;
#pragma unroll
            for (int off = 1; off < 16; off <<= 1) {
                int t = __shfl_up(s, off, 64);
                if (lane >= off) s += t;
            }
            if (lane < 16) wsum[lane] = s;
        }
        __syncthreads();
        const int woff = (wv > 0) ? wsum[wv - 1] : 0;
        const int total = wsum[15];
        if (i < N) {
            int ex = running + woff + x - v;
            row_ptr[i] = ex;
            cursor[i] = ex;
        }
        running += total;
        __syncthreads();
    }
    if (tid == 0) row_ptr[N] = running;
}

__global__ void scatter_kernel(const int* __restrict__ src, const int* __restrict__ dst,
                               int* __restrict__ cursor, int* __restrict__ csr, int E) {
    int e = blockIdx.x * blockDim.x + threadIdx.x;
    if (e < E) {
        int p = atomicAdd(&cursor[dst[e]], 1);
        csr[p] = src[e];
    }
}

// Fused: x split + weight transposes/splits + cnt zero.
__global__ void prep_all(const float* __restrict__ x, int nx4,
                         ushort* __restrict__ x_hi, ushort* __restrict__ x_lo,
                         const float* __restrict__ W1a, const float* __restrict__ W1b,
                         const float* __restrict__ W2a, const float* __restrict__ W2b,
                         ushort* __restrict__ T1a_h, ushort* __restrict__ T1a_l,
                         ushort* __restrict__ T1b_h,
                         ushort* __restrict__ T2a_h,
                         ushort* __restrict__ T2b_h, ushort* __restrict__ T2b_l,
                         int* __restrict__ cnt, int N) {
    int i = blockIdx.x * blockDim.x + threadIdx.x;
    if (i < nx4) {
        float4 v = ((const float4*)x)[i];
        ushort4 h, l;
        split2(v.x, h.x, l.x);
        split2(v.y, h.y, l.y);
        split2(v.z, h.z, l.z);
        split2(v.w, h.w, l.w);
        ((ushort4*)x_hi)[i] = h;
        ((ushort4*)x_lo)[i] = l;
        return;
    }
    int j = i - nx4;
    if (j < 65536) {  // T1a [n<512][k<128] hi/lo; src W1a [256][256]
        int n = j >> 7, k = j & 127;
        float v = (n < 256) ? W1a[k * 256 + n] : W1a[(128 + k) * 256 + (n - 256)];
        ushort h, l;
        split2(v, h, l);
        T1a_h[j] = h;
        T1a_l[j] = l;
        return;
    }
    if (j < 131072) {  // T1b [n<256][k<256] hi only; src W1b [256][256]
        int t = j - 65536;
        int n = t >> 8, k = t & 255;
        T1b_h[t] = f2bf_rne(W1b[k * 256 + n]);
        return;
    }
    if (j < 196608) {  // T2a [n<256][k<256] hi only; src W2a [512][128]
        int t = j - 131072;
        int n = t >> 8, k = t & 255;
        float v = (n < 128) ? W2a[k * 128 + n] : W2a[(256 + k) * 128 + (n - 128)];
        T2a_h[t] = f2bf_rne(v);
        return;
    }
    if (j < 212992) {  // T2b [n<128][k<128] hi/lo; src W2b [128][128]
        int t = j - 196608;
        int n = t >> 7, k = t & 127;
        ushort h, l;
        split2(W2b[k * 128 + n], h, l);
        T2b_h[t] = h;
        T2b_l[t] = l;
        return;
    }
    int k = j - 212992;
    if (k < N) cnt[k] = 0;
}

// ---------------- bf16 MFMA GEMM (1-pass or 3-pass compensated) ----------------
// A[M][K] bf16 (hi, + lo if THREE); B transposed [Nc][K] (hi, + lo if THREE).
// Tile BM=128,BN=64,BK=32; 4 waves. MODE 0: f32 out (+bias,+gate,+relu).
// MODE 1: dual — col<nsplit -> f32+bias; col>=nsplit -> FP16 (gather payload).
// MODE 2: hi/lo bf16 out. MODE 3: bf16 out (+bias,+gate,+relu).

#define GBM 128
#define GBN 64
#define GBK 32
#define LDSW 40

template <int MODE, int THREE>
__global__ __launch_bounds__(256) void gemm_bf3(
    const ushort* __restrict__ Ahi, const ushort* __restrict__ Alo, int M, int K,
    const ushort* __restrict__ BThi, const ushort* __restrict__ BTlo,
    const float* __restrict__ bias, const int* __restrict__ gate, int relu,
    float* __restrict__ Cf, ushort* __restrict__ Chi, ushort* __restrict__ Clo,
    int Nc, int nsplit) {
    __shared__ ushort sAh[GBM * LDSW];
    __shared__ ushort sBh[GBN * LDSW];
    __shared__ ushort sAl[THREE ? GBM * LDSW : 1];
    __shared__ ushort sBl[THREE ? GBN * LDSW : 1];

    const int tid = threadIdx.x;
    const int lane = tid & 63;
    const int w = tid >> 6;
    const int wm = w >> 1, wn = w & 1;
    const int r16 = lane & 15, kg = lane >> 4;
    const int m0 = blockIdx.x * GBM;
    const int n0 = blockIdx.y * GBN;

    const int arow = tid >> 1, ahalf = tid & 1;   // A: 2 thr/row, 16 ushorts (2x int4)
    const int brow = tid >> 2, bchunk = tid & 3;  // B: 4 thr/row, 8 ushorts (1x int4)

    f32x4 acc[4][2];
#pragma unroll
    for (int i = 0; i < 4; i++)
#pragma unroll
        for (int j = 0; j < 2; j++) acc[i][j] = (f32x4)0.f;

    for (int kt = 0; kt < K; kt += GBK) {
        {
            const int gr = m0 + arow;
            const size_t go = (size_t)gr * K + kt + ahalf * 16;
            int4 h0 = make_int4(0, 0, 0, 0), h1 = h0;
            if (gr < M) {
                h0 = *(const int4*)(Ahi + go);
                h1 = *(const int4*)(Ahi + go + 8);
            }
            ushort* dh = sAh + arow * LDSW + ahalf * 16;
            *(int4*)(dh) = h0;
            *(int4*)(dh + 8) = h1;
            if constexpr (THREE) {
                int4 l0 = make_int4(0, 0, 0, 0), l1 = l0;
                if (gr < M) {
                    l0 = *(const int4*)(Alo + go);
                    l1 = *(const int4*)(Alo + go + 8);
                }
                ushort* dl = sAl + arow * LDSW + ahalf * 16;
                *(int4*)(dl) = l0;
                *(int4*)(dl + 8) = l1;
            }
        }
        {
            const size_t go = (size_t)(n0 + brow) * K + kt + bchunk * 8;
            *(int4*)(sBh + brow * LDSW + bchunk * 8) = *(const int4*)(BThi + go);
            if constexpr (THREE) {
                *(int4*)(sBl + brow * LDSW + bchunk * 8) = *(const int4*)(BTlo + go);
            }
        }
        __syncthreads();

        bf16x8 ah[4], bh[2];
#pragma unroll
        for (int mi = 0; mi < 4; mi++)
            ah[mi] = *(const bf16x8*)(sAh + (wm * 64 + mi * 16 + r16) * LDSW + kg * 8);
#pragma unroll
        for (int ni = 0; ni < 2; ni++)
            bh[ni] = *(const bf16x8*)(sBh + (wn * 32 + ni * 16 + r16) * LDSW + kg * 8);

        if constexpr (THREE) {
            bf16x8 al[4], bl[2];
#pragma unroll
            for (int mi = 0; mi < 4; mi++)
                al[mi] = *(const bf16x8*)(sAl + (wm * 64 + mi * 16 + r16) * LDSW + kg * 8);
#pragma unroll
            for (int ni = 0; ni < 2; ni++)
                bl[ni] = *(const bf16x8*)(sBl + (wn * 32 + ni * 16 + r16) * LDSW + kg * 8);
#pragma unroll
            for (int mi = 0; mi < 4; mi++)
#pragma unroll
                for (int ni = 0; ni < 2; ni++) {
                    acc[mi][ni] = __builtin_amdgcn_mfma_f32_16x16x32_bf16(ah[mi], bh[ni], acc[mi][ni], 0, 0, 0);
                    acc[mi][ni] = __builtin_amdgcn_mfma_f32_16x16x32_bf16(ah[mi], bl[ni], acc[mi][ni], 0, 0, 0);
                    acc[mi][ni] = __builtin_amdgcn_mfma_f32_16x16x32_bf16(al[mi], bh[ni], acc[mi][ni], 0, 0, 0);
                }
        } else {
#pragma unroll
            for (int mi = 0; mi < 4; mi++)
#pragma unroll
                for (int ni = 0; ni < 2; ni++)
                    acc[mi][ni] = __builtin_amdgcn_mfma_f32_16x16x32_bf16(ah[mi], bh[ni], acc[mi][ni], 0, 0, 0);
        }
        __syncthreads();
    }

    // epilogue: C/D mapping col=lane&15, row=(lane>>4)*4+reg  [m89-verified]
#pragma unroll
    for (int ni = 0; ni < 2; ni++) {
        const int col = n0 + wn * 32 + ni * 16 + r16;
        float bv = 0.f;
        if constexpr (MODE == 1) {
            bv = (col < nsplit && bias) ? bias[col] : 0.f;
        } else {
            bv = bias ? bias[col] : 0.f;
        }
#pragma unroll
        for (int mi = 0; mi < 4; mi++) {
#pragma unroll
            for (int r = 0; r < 4; r++) {
                const int row = m0 + wm * 64 + mi * 16 + kg * 4 + r;
                if (row >= M) continue;
                if constexpr (MODE == 1) {
                    const float v = acc[mi][ni][r];
                    if (col < nsplit) {
                        Cf[(size_t)row * nsplit + col] = v + bv;
                    } else {
                        // fp16 gather payload
                        _Float16 hv = (_Float16)v;
                        Chi[(size_t)row * (Nc - nsplit) + (col - nsplit)] =
                            __builtin_bit_cast(ushort, hv);
                    }
                } else {
                    float g = 1.f;
                    if (gate) g = (gate[row] > 0) ? 1.f : 0.f;
                    float v = acc[mi][ni][r] + bv * g;
                    if (relu) v = fmaxf(v, 0.f);
                    const size_t o = (size_t)row * Nc + col;
                    if constexpr (MODE == 0) {
                        Cf[o] = v;
                    } else if constexpr (MODE == 3) {
                        Chi[o] = f2bf_rne(v);
                    } else {
                        ushort h, l;
                        split2(v, h, l);
                        Chi[o] = h;
                        Clo[o] = l;
                    }
                }
            }
        }
    }
}

// ---------------- CSR mean aggregation: full-row waves, uniform edge loop -------
// Wave = one node's full H-feature row (lane = feature column, VPL feats/lane).
// 2 waves per node split the edge list by 8-edge groups; edge indices are
// wave-uniform (scalar loads), gathers are fully coalesced H*2-byte rows.
// Math in packed _Float16x2 (Pbot is fp16), f32 flush per 8-edge group.
// SPLIT: 1 -> write hi/lo bf16, 0 -> hi only.

template <int H, int SPLIT>
__global__ __launch_bounds__(256) void agg_f(const float* __restrict__ Ptop,
                                             const ushort* __restrict__ Pbot,
                                             const int* __restrict__ row_ptr,
                                             const int* __restrict__ csr,
                                             ushort* __restrict__ Shi,
                                             ushort* __restrict__ Slo, int N) {
    constexpr int VPL = H / 64;  // feats per lane: 4 (H=256) or 2 (H=128)
    __shared__ float red[2][64 * VPL];

    const int tid = threadIdx.x;
    const int lane = tid & 63;
    const int wv = __builtin_amdgcn_readfirstlane(tid >> 6);
    const int nb = wv >> 1;   // node within block (0,1)
    const int sub = wv & 1;   // edge-split half
    int n = blockIdx.x * 2 + nb;
    if (n >= N) n = N - 1;  // duplicate work on odd tail; benign identical writes

    const int begin = row_ptr[n];
    const int end = row_ptr[n + 1];
    const int deg = end - begin;

    h2 t01, t23;
    if constexpr (VPL == 4) {
        float4 tf = *(const float4*)(Ptop + (size_t)n * H + lane * 4);
        t01 = (h2){(_Float16)tf.x, (_Float16)tf.y};
        t23 = (h2){(_Float16)tf.z, (_Float16)tf.w};
    } else {
        float2 tf = *(const float2*)(Ptop + (size_t)n * H + lane * 2);
        t01 = (h2){(_Float16)tf.x, (_Float16)tf.y};
        t23 = t01;
    }
    const h2 z2 = (h2)(_Float16)0.f;

    float a0 = 0.f, a1 = 0.f, a2 = 0.f, a3 = 0.f;
    const ushort* pb = Pbot + lane * VPL;

    const int Gf = deg >> 3;   // full 8-edge groups
    const int r = deg & 7;

    for (int g = sub; g < Gf; g += 2) {
        const int e = begin + g * 8;
        h2 p01 = z2, p23 = z2;
#pragma unroll
        for (int j = 0; j < 8; j++) {
            const int idx = csr[e + j];
            if constexpr (VPL == 4) {
                uint2 u = *(const uint2*)(pb + (size_t)idx * H);
                p01 += __builtin_elementwise_max(t01 + bc2(u.x), z2);
                p23 += __builtin_elementwise_max(t23 + bc2(u.y), z2);
            } else {
                unsigned u = *(const unsigned*)(pb + (size_t)idx * H);
                p01 += __builtin_elementwise_max(t01 + bc2(u), z2);
            }
        }
        a0 += (float)p01.x;
        a1 += (float)p01.y;
        if constexpr (VPL == 4) {
            a2 += (float)p23.x;
            a3 += (float)p23.y;
        }
    }
    if (r && sub == (Gf & 1)) {  // tail goes to the wave with fewer groups
        const int e = begin + Gf * 8;
        h2 p01 = z2, p23 = z2;
        for (int j = 0; j < r; j++) {
            const int idx = csr[e + j];
            if constexpr (VPL == 4) {
                uint2 u = *(const uint2*)(pb + (size_t)idx * H);
                p01 += __builtin_elementwise_max(t01 + bc2(u.x), z2);
                p23 += __builtin_elementwise_max(t23 + bc2(u.y), z2);
            } else {
                unsigned u = *(const unsigned*)(pb + (size_t)idx * H);
                p01 += __builtin_elementwise_max(t01 + bc2(u), z2);
            }
        }
        a0 += (float)p01.x;
        a1 += (float)p01.y;
        if constexpr (VPL == 4) {
            a2 += (float)p23.x;
            a3 += (float)p23.y;
        }
    }

    // combine the two edge-split waves via LDS
    if (sub == 1) {
        red[nb][lane * VPL + 0] = a0;
        red[nb][lane * VPL + 1] = a1;
        if constexpr (VPL == 4) {
            red[nb][lane * VPL + 2] = a2;
            red[nb][lane * VPL + 3] = a3;
        }
    }
    __syncthreads();
    if (sub == 0) {
        a0 += red[nb][lane * VPL + 0];
        a1 += red[nb][lane * VPL + 1];
        if constexpr (VPL == 4) {
            a2 += red[nb][lane * VPL + 2];
            a3 += red[nb][lane * VPL + 3];
        }
        const float inv = (deg > 0) ? 1.f / (float)deg : 0.f;
        if constexpr (VPL == 4) {
            if constexpr (SPLIT) {
                ushort4 h, l;
                split2(a0 * inv, h.x, l.x);
                split2(a1 * inv, h.y, l.y);
                split2(a2 * inv, h.z, l.z);
                split2(a3 * inv, h.w, l.w);
                *(ushort4*)(Shi + (size_t)n * H + lane * 4) = h;
                *(ushort4*)(Slo + (size_t)n * H + lane * 4) = l;
            } else {
                ushort4 h;
                h.x = f2bf_rne(a0 * inv);
                h.y = f2bf_rne(a1 * inv);
                h.z = f2bf_rne(a2 * inv);
                h.w = f2bf_rne(a3 * inv);
                *(ushort4*)(Shi + (size_t)n * H + lane * 4) = h;
            }
        } else {
            if constexpr (SPLIT) {
                ushort2 h, l;
                split2(a0 * inv, h.x, l.x);
                split2(a1 * inv, h.y, l.y);
                *(ushort2*)(Shi + (size_t)n * H + lane * 2) = h;
                *(ushort2*)(Slo + (size_t)n * H + lane * 2) = l;
            } else {
                ushort2 h;
                h.x = f2bf_rne(a0 * inv);
                h.y = f2bf_rne(a1 * inv);
                *(ushort2*)(Shi + (size_t)n * H + lane * 2) = h;
            }
        }
    }
}

// ---------------- launch ----------------

extern "C" void kernel_launch(void* const* d_in, const int* in_sizes, int n_in,
                              void* d_out, int out_size, void* d_ws, size_t ws_size,
                              hipStream_t stream) {
    const int N = in_sizes[0] / NODE_DIM;  // 20000
    const int E = in_sizes[1] / 2;         // 640000

    const float* x = (const float*)d_in[0];
    const int* ei = (const int*)d_in[1];
    const int* e_src = ei;
    const int* e_dst = ei + E;
    const float* W1a = (const float*)d_in[2];
    const float* b1a = (const float*)d_in[3];
    const float* W1b = (const float*)d_in[4];
    const float* b1b = (const float*)d_in[5];
    const float* W2a = (const float*)d_in[6];
    const float* b2a = (const float*)d_in[7];
    const float* W2b = (const float*)d_in[8];
    const float* b2b = (const float*)d_in[9];

    char* ws = (char*)d_ws;
    size_t off = 0;
    auto alloc = [&](size_t bytes) {
        size_t o = off;
        off += (bytes + 255) & ~(size_t)255;
        return o;
    };
    int* cnt = (int*)(ws + alloc((size_t)N * 4));
    int* row_ptr = (int*)(ws + alloc((size_t)(N + 1) * 4));
    int* cursor = (int*)(ws + alloc((size_t)N * 4));
    int* csr = (int*)(ws + alloc((size_t)E * 4));
    ushort* x_hi = (ushort*)(ws + alloc((size_t)N * NODE_DIM * 2));
    ushort* x_lo = (ushort*)(ws + alloc((size_t)N * NODE_DIM * 2));
    ushort* T1a_h = (ushort*)(ws + alloc((size_t)(2 * HID) * NODE_DIM * 2));  // [512][128]
    ushort* T1a_l = (ushort*)(ws + alloc((size_t)(2 * HID) * NODE_DIM * 2));
    ushort* T1b_h = (ushort*)(ws + alloc((size_t)HID * HID * 2));
    ushort* T2a_h = (ushort*)(ws + alloc((size_t)(2 * OUTD) * HID * 2));  // [256][256]
    ushort* T2b_h = (ushort*)(ws + alloc((size_t)OUTD * OUTD * 2));
    ushort* T2b_l = (ushort*)(ws + alloc((size_t)OUTD * OUTD * 2));
    float* P1t = (float*)(ws + alloc((size_t)N * HID * 4));
    ushort* P1b = (ushort*)(ws + alloc((size_t)N * HID * 2));   // fp16
    ushort* P2b = (ushort*)(ws + alloc((size_t)N * OUTD * 2));  // fp16
    ushort* S1h = (ushort*)(ws + alloc((size_t)N * HID * 2));
    ushort* S2l = (ushort*)(ws + alloc((size_t)N * OUTD * 2));
    ushort* h_hi = (ushort*)(ws + alloc((size_t)N * HID * 2));
    float* P2t = P1t;
    ushort* S2h = S1h;

    // prep (cnt zero inside) -> CSR build
    const int nx4 = N * NODE_DIM / 4;
    const int prep_n = nx4 + 212992 + N;
    prep_all<<<(prep_n + 255) / 256, 256, 0, stream>>>(
        x, nx4, x_hi, x_lo, W1a, W1b, W2a, W2b,
        T1a_h, T1a_l, T1b_h, T2a_h, T2b_h, T2b_l, cnt, N);
    hist_kernel<<<(E + 255) / 256, 256, 0, stream>>>(e_dst, cnt, E);
    scan_kernel<<<1, 1024, 0, stream>>>(cnt, row_ptr, cursor, N);
    scatter_kernel<<<(E + 255) / 256, 256, 0, stream>>>(e_src, e_dst, cursor, csr, E);

    const int MT = (N + GBM - 1) / GBM;  // 157
    const int AG = (N + 1) / 2;          // agg blocks: 2 nodes x 2 edge-split waves

    // Layer 1: merged projection, 3-pass (x is the largest error source)
    gemm_bf3<1, 1><<<dim3(MT, (2 * HID) / GBN), 256, 0, stream>>>(
        x_hi, x_lo, N, NODE_DIM, T1a_h, T1a_l, b1a, nullptr, 0,
        P1t, P1b, nullptr, 2 * HID, HID);
    agg_f<HID, 0><<<AG, 256, 0, stream>>>(P1t, P1b, row_ptr, csr, S1h, nullptr, N);
    // S1@W1b: 1-pass bf16 -> h (bf16, bias gated, relu)
    gemm_bf3<3, 0><<<dim3(MT, HID / GBN), 256, 0, stream>>>(
        S1h, nullptr, N, HID, T1b_h, nullptr, b1b, cnt, 1,
        nullptr, h_hi, nullptr, HID, 0);

    // Layer 2: merged projection, 1-pass
    gemm_bf3<1, 0><<<dim3(MT, (2 * OUTD) / GBN), 256, 0, stream>>>(
        h_hi, nullptr, N, HID, T2a_h, nullptr, b2a, nullptr, 0,
        P2t, P2b, nullptr, 2 * OUTD, OUTD);
    agg_f<OUTD, 1><<<AG, 256, 0, stream>>>(P2t, P2b, row_ptr, csr, S2h, S2l, N);
    // final GEMM: 3-pass (direct to output)
    gemm_bf3<0, 1><<<dim3(MT, OUTD / GBN), 256, 0, stream>>>(
        S2h, S2l, N, OUTD, T2b_h, T2b_l, b2b, cnt, 0,
        (float*)d_out, nullptr, nullptr, OUTD, 0);
}